// Round 1
// baseline (3261.742 us; speedup 1.0000x reference)
//
#include <hip/hip_runtime.h>
#include <math.h>

#define DI __device__ __forceinline__

constexpr int B = 16, H = 41, W = 40, C = 48, M1 = 12, M2 = 12, NL = 4;
constexpr int HW = H * W;                  // 1640
constexpr float EPS = 1e-5f;
constexpr float PI_F = 3.14159265358979323846f;

// ---------------- static device scratch (compile-time shapes) ----------------
__device__ float  g_h[2][B * C * HW];      // ping-pong activations [b][c][hw]
__device__ float2 g_alpha[B * C * HW];     // fft2(inorm(h))
__device__ float2 g_inv1[C * C * M1 * H];  // [i*C+k][p][o]
__device__ float2 g_inv2[C * C * M2 * W];  // [i*C+k][q][x]
__device__ float2 g_E1[C * C * M1 * H];    // exp(p1 * TX)
__device__ float2 g_E2[C * C * M2 * W];    // exp(p2 * TY)
__device__ float2 g_S[C * C * HW];         // [i*C+k][o*W+x]
__device__ float2 g_res1[B * C * HW];
__device__ float  g_x1[B * C * HW];        // pr2d output accumulator (real)
__device__ float2 g_r2[B * C * M1 * M2];
__device__ float  g_mu[B * C];
__device__ float  g_rstd[B * C];
__device__ float2 g_wfh[H * H];            // e^{-2pi i o h / H}
__device__ float2 g_wfw[W * W];            // e^{-2pi i x w / W}

// ---------------- complex helpers ----------------
DI float2 cmadd(float2 a, float2 b, float2 acc) {
    acc.x = fmaf(a.x, b.x, fmaf(-a.y, b.y, acc.x));
    acc.y = fmaf(a.x, b.y, fmaf(a.y, b.x, acc.y));
    return acc;
}

// ---------------- twiddle tables ----------------
__global__ void k_tw() {
    int tid = blockIdx.x * 256 + threadIdx.x;
    if (tid < H * H) {
        int o = tid / H, h = tid % H;
        float ph = -2.0f * PI_F * (float)((o * h) % H) / (float)H;
        float s, c; sincosf(ph, &s, &c);
        g_wfh[tid] = make_float2(c, s);
    }
    int t2 = tid - H * H;
    if (t2 >= 0 && t2 < W * W) {
        int o = t2 / W, w = t2 % W;
        float ph = -2.0f * PI_F * (float)((o * w) % W) / (float)W;
        float s, c; sincosf(ph, &s, &c);
        g_wfw[t2] = make_float2(c, s);
    }
}

// ---------------- fc0 + grid concat ----------------
__global__ void k_fc0(const float* __restrict__ x, const float* __restrict__ w,
                      const float* __restrict__ bias) {
    int idx = blockIdx.x * 256 + threadIdx.x;
    if (idx >= B * C * HW) return;
    int hw = idx % HW; int bc = idx / HW; int c = bc % C; int b = bc / C;
    int hh = hw / W, ww = hw % W;
    float xv = x[b * HW + hw];
    float gx = hh * (1.0f / (H - 1));
    float gy = ww * (1.0f / (W - 1));
    g_h[0][idx] = fmaf(w[c * 3 + 0], xv, fmaf(w[c * 3 + 1], gx, fmaf(w[c * 3 + 2], gy, bias[c])));
}

// ---------------- instance-norm + fft2 (per b,c) ----------------
__global__ __launch_bounds__(256) void k_fft(int src) {
    int bid = blockIdx.x;                  // b*C + c
    const float* hp = &g_h[src][(size_t)bid * HW];
    __shared__ float sh[HW];
    __shared__ float2 st[HW];
    __shared__ float red[8];
    int tid = threadIdx.x;
    float s = 0.f, ss = 0.f;
    for (int i = tid; i < HW; i += 256) { float v = hp[i]; sh[i] = v; s += v; ss += v * v; }
    for (int off = 32; off; off >>= 1) { s += __shfl_down(s, off); ss += __shfl_down(ss, off); }
    if ((tid & 63) == 0) { red[tid >> 6] = s; red[4 + (tid >> 6)] = ss; }
    __syncthreads();
    if (tid == 0) {
        float S = red[0] + red[1] + red[2] + red[3];
        float SS = red[4] + red[5] + red[6] + red[7];
        float mean = S * (1.0f / HW);
        float var = SS * (1.0f / HW) - mean * mean;
        red[0] = mean; red[1] = rsqrtf(var + EPS);
    }
    __syncthreads();
    float mean = red[0], rstd = red[1];
    for (int i = tid; i < HW; i += 256) sh[i] = (sh[i] - mean) * rstd;
    __syncthreads();
    // row DFT over h: st[o*W+w] = sum_h wfh[o,h] * sh[h,w]
    for (int i = tid; i < HW; i += 256) {
        int o = i / W, w = i % W;
        float2 acc = make_float2(0.f, 0.f);
        for (int h = 0; h < H; h++) {
            float v = sh[h * W + w];
            float2 tw = g_wfh[o * H + h];
            acc.x = fmaf(tw.x, v, acc.x); acc.y = fmaf(tw.y, v, acc.y);
        }
        st[i] = acc;
    }
    __syncthreads();
    // col DFT over w: alpha[o*W+x] = sum_w st[o,w] * wfw[x,w]
    float2* ap = &g_alpha[(size_t)bid * HW];
    for (int i = tid; i < HW; i += 256) {
        int o = i / W, x = i % W;
        float2 acc = make_float2(0.f, 0.f);
        for (int w = 0; w < W; w++) acc = cmadd(st[o * W + w], g_wfw[x * W + w], acc);
        ap[i] = acc;
    }
}

// ---------------- pole tables: inv1, inv2, E1, E2 (per i,k pair) ----------------
__global__ void k_tables(const float* __restrict__ p1, const float* __restrict__ p2, int l) {
    int pk = blockIdx.x;                   // i*C + k
    int tid = threadIdx.x;
    const float* pp1 = p1 + (size_t)(l * C * C + pk) * M1 * 2;
    const float* pp2 = p2 + (size_t)(l * C * C + pk) * M2 * 2;
    float2* inv1 = &g_inv1[(size_t)pk * M1 * H];
    float2* e1   = &g_E1[(size_t)pk * M1 * H];
    for (int i = tid; i < M1 * H; i += 256) {
        int p = i / H, o = i % H;
        float pr = pp1[p * 2], pi = pp1[p * 2 + 1];
        int ko = (o <= H / 2) ? o : o - H;           // fftfreq, H=41 odd
        float lam = (40.0f / 41.0f) * (float)ko;     // Im(LAM1)
        float a = -pr, b = lam - pi;
        float d = 1.0f / (a * a + b * b);
        inv1[i] = make_float2(a * d, -b * d);
        float t = o * (2.0f * PI_F / (H - 1));       // TX[z]
        float er = expf(pr * t);
        float sn, cs; sincosf(pi * t, &sn, &cs);
        e1[i] = make_float2(er * cs, er * sn);
    }
    float2* inv2 = &g_inv2[(size_t)pk * M2 * W];
    float2* e2   = &g_E2[(size_t)pk * M2 * W];
    for (int i = tid; i < M2 * W; i += 256) {
        int q = i / W, x = i % W;
        float pr = pp2[q * 2], pi = pp2[q * 2 + 1];
        int kx = (x < W / 2) ? x : x - W;            // fftfreq, W=40 even
        float lam = (2.0f * PI_F * 39.0f / 600.0f) * (float)kx;  // Im(LAM2)
        float a = -pr, b = lam - pi;
        float d = 1.0f / (a * a + b * b);
        inv2[i] = make_float2(a * d, -b * d);
        float t = x * (15.0f / (W - 1));             // TY[x]
        float er = expf(pr * t);
        float sn, cs; sincosf(pi * t, &sn, &cs);
        e2[i] = make_float2(er * cs, er * sn);
    }
}

// ---------------- S[i,k,o,x] = sum_p inv1[p,o] * (sum_q res[p,q] inv2[q,x]) ----------------
__global__ __launch_bounds__(256) void k_S(const float* __restrict__ res_in, int l) {
    int pk = blockIdx.x;
    int tid = threadIdx.x;
    __shared__ float2 sres[M1 * M2], sinv1[M1 * H], sinv2[M2 * W], sT[M1 * W];
    const float2* rp = (const float2*)res_in + (size_t)(l * C * C + pk) * M1 * M2;
    for (int i = tid; i < M1 * M2; i += 256) sres[i] = rp[i];
    for (int i = tid; i < M1 * H; i += 256) sinv1[i] = g_inv1[(size_t)pk * M1 * H + i];
    for (int i = tid; i < M2 * W; i += 256) sinv2[i] = g_inv2[(size_t)pk * M2 * W + i];
    __syncthreads();
    for (int i = tid; i < M1 * W; i += 256) {
        int p = i / W, x = i % W;
        float2 acc = make_float2(0.f, 0.f);
        for (int q = 0; q < M2; q++) acc = cmadd(sres[p * M2 + q], sinv2[q * W + x], acc);
        sT[i] = acc;
    }
    __syncthreads();
    float2* sp = &g_S[(size_t)pk * HW];
    for (int i = tid; i < HW; i += 256) {
        int o = i / W, x = i % W;
        float2 acc = make_float2(0.f, 0.f);
        for (int p = 0; p < M1; p++) acc = cmadd(sinv1[p * H + o], sT[p * W + x], acc);
        sp[i] = acc;
    }
}

// ---------------- res1[b,k,ox] = sum_i alpha[b,i,ox] * S[i,k,ox] ----------------
__global__ __launch_bounds__(256) void k_res1() {
    int bid = blockIdx.x; int k = bid % C, b = bid / C;
    int tid = threadIdx.x;
    float2 acc[7];
#pragma unroll
    for (int j = 0; j < 7; j++) acc[j] = make_float2(0.f, 0.f);
    for (int i = 0; i < C; i++) {
        const float2* ap = &g_alpha[(size_t)(b * C + i) * HW];
        const float2* sp = &g_S[(size_t)(i * C + k) * HW];
#pragma unroll
        for (int j = 0; j < 7; j++) {
            int idx = tid + j * 256;
            if (idx < HW) acc[j] = cmadd(ap[idx], sp[idx], acc[j]);
        }
    }
    float2* rp = &g_res1[(size_t)bid * HW];
#pragma unroll
    for (int j = 0; j < 7; j++) { int idx = tid + j * 256; if (idx < HW) rp[idx] = acc[j]; }
}

// ---------------- x1 = ifft2(res1).real ----------------
__global__ __launch_bounds__(256) void k_ifft() {
    int bid = blockIdx.x; int tid = threadIdx.x;
    __shared__ float2 s0[HW], s1[HW];
    const float2* rp = &g_res1[(size_t)bid * HW];
    for (int i = tid; i < HW; i += 256) s0[i] = rp[i];
    __syncthreads();
    // inverse over o: s1[h,x] = sum_o s0[o,x] * conj(wfh[o,h])
    for (int i = tid; i < HW; i += 256) {
        int h = i / W, x = i % W;
        float2 acc = make_float2(0.f, 0.f);
        for (int o = 0; o < H; o++) {
            float2 v = s0[o * W + x]; float2 tw = g_wfh[o * H + h];
            acc.x = fmaf(v.x, tw.x, fmaf(v.y, tw.y, acc.x));
            acc.y = fmaf(v.y, tw.x, fmaf(-v.x, tw.y, acc.y));
        }
        s1[i] = acc;
    }
    __syncthreads();
    float* xp = &g_x1[(size_t)bid * HW];
    for (int i = tid; i < HW; i += 256) {
        int h = i / W, w = i % W;
        float acc = 0.f;
        for (int x = 0; x < W; x++) {
            float2 v = s1[h * W + x]; float2 tw = g_wfw[x * W + w];
            acc = fmaf(v.x, tw.x, fmaf(v.y, tw.y, acc));  // Re(v * conj(tw))
        }
        xp[i] = acc * (1.0f / (H * W));
    }
}

// ---------------- r2[b,k,p,q] = sum_i res[i,k,p,q] * (inv1 @ alpha[b,i] @ inv2^T)[p,q] ----------------
__global__ __launch_bounds__(256) void k_r2(const float* __restrict__ res_in, int l) {
    int bid = blockIdx.x; int k = bid % C, b = bid / C;
    int tid = threadIdx.x;
    __shared__ float2 sa[HW];
    __shared__ float2 si1[M1 * H];
    __shared__ float2 si2[M2 * W];
    __shared__ float2 sY[M1 * W];
    __shared__ float2 sacc[M1 * M2];
    for (int i = tid; i < M1 * M2; i += 256) sacc[i] = make_float2(0.f, 0.f);
    for (int ci = 0; ci < C; ci++) {
        const float2* ap = &g_alpha[(size_t)(b * C + ci) * HW];
        for (int i = tid; i < HW; i += 256) sa[i] = ap[i];
        int pk = ci * C + k;
        for (int i = tid; i < M1 * H; i += 256) si1[i] = g_inv1[(size_t)pk * M1 * H + i];
        for (int i = tid; i < M2 * W; i += 256) si2[i] = g_inv2[(size_t)pk * M2 * W + i];
        __syncthreads();
        // Y[p,x] = sum_o inv1[p,o] * alpha[o,x]
        for (int i = tid; i < M1 * W; i += 256) {
            int p = i / W, x = i % W;
            float2 acc = make_float2(0.f, 0.f);
            for (int o = 0; o < H; o++) acc = cmadd(si1[p * H + o], sa[o * W + x], acc);
            sY[i] = acc;
        }
        __syncthreads();
        // Z[p,q] = sum_x Y[p,x] * inv2[q,x];  acc += res * Z
        const float2* rp = (const float2*)res_in + (size_t)(l * C * C + pk) * M1 * M2;
        for (int i = tid; i < M1 * M2; i += 256) {
            int p = i / M2, q = i % M2;
            float2 z = make_float2(0.f, 0.f);
            for (int x = 0; x < W; x++) z = cmadd(sY[p * W + x], si2[q * W + x], z);
            sacc[i] = cmadd(rp[i], z, sacc[i]);
        }
        __syncthreads();
    }
    float2* out = &g_r2[(size_t)bid * M1 * M2];
    for (int i = tid; i < M1 * M2; i += 256) out[i] = sacc[i];
}

// ---------------- x2 accumulate + finalize pr + per-(b,c) stats ----------------
__global__ __launch_bounds__(256) void k_x2() {
    int bid = blockIdx.x; int k = bid % C, b = bid / C;
    int tid = threadIdx.x;
    __shared__ float saccr[HW];
    __shared__ float2 sE1[M1 * H];
    __shared__ float2 sE2[M2 * W];
    __shared__ float2 sV[M1 * W];
    __shared__ float2 sr2[M1 * M2];
    __shared__ float red[8];
    for (int i = tid; i < HW; i += 256) saccr[i] = 0.f;
    for (int ci = 0; ci < C; ci++) {
        int pk = ci * C + k;
        const float2* rp = &g_r2[(size_t)(b * C + ci) * M1 * M2];
        for (int i = tid; i < M1 * M2; i += 256) sr2[i] = rp[i];
        for (int i = tid; i < M1 * H; i += 256) sE1[i] = g_E1[(size_t)pk * M1 * H + i];
        for (int i = tid; i < M2 * W; i += 256) sE2[i] = g_E2[(size_t)pk * M2 * W + i];
        __syncthreads();
        // V[p,x] = sum_q r2[p,q] * E2[q,x]
        for (int i = tid; i < M1 * W; i += 256) {
            int p = i / W, x = i % W;
            float2 acc = make_float2(0.f, 0.f);
            for (int q = 0; q < M2; q++) acc = cmadd(sr2[p * M2 + q], sE2[q * W + x], acc);
            sV[i] = acc;
        }
        __syncthreads();
        // accr[z,x] += Re( sum_p E1[p,z] * V[p,x] )
        for (int i = tid; i < HW; i += 256) {
            int z = i / W, x = i % W;
            float acc = saccr[i];
            for (int p = 0; p < M1; p++) {
                float2 e = sE1[p * H + z]; float2 v = sV[p * W + x];
                acc = fmaf(e.x, v.x, fmaf(-e.y, v.y, acc));
            }
            saccr[i] = acc;
        }
        __syncthreads();
    }
    // pr = x1 + x2/(H*W); write back; reduce stats for instance norm
    float* xp = &g_x1[(size_t)bid * HW];
    float s = 0.f, ss = 0.f;
    for (int i = tid; i < HW; i += 256) {
        float v = xp[i] + saccr[i] * (1.0f / (H * W));
        xp[i] = v; s += v; ss += v * v;
    }
    for (int off = 32; off; off >>= 1) { s += __shfl_down(s, off); ss += __shfl_down(ss, off); }
    if ((tid & 63) == 0) { red[tid >> 6] = s; red[4 + (tid >> 6)] = ss; }
    __syncthreads();
    if (tid == 0) {
        float S = red[0] + red[1] + red[2] + red[3];
        float SS = red[4] + red[5] + red[6] + red[7];
        float mean = S * (1.0f / HW);
        float var = SS * (1.0f / HW) - mean * mean;
        g_mu[bid] = mean; g_rstd[bid] = rsqrtf(var + EPS);
    }
}

// ---------------- h_next = sin( inorm(pr) + conv(h) + conv_b ) ----------------
constexpr int TILE = 128;
constexpr int NTILE = (HW + TILE - 1) / TILE;   // 13
__global__ __launch_bounds__(256) void k_comb(const float* __restrict__ cw,
                                              const float* __restrict__ cb, int l, int src) {
    int b = blockIdx.x / NTILE;
    int t0 = (blockIdx.x % NTILE) * TILE;
    int tid = threadIdx.x;
    __shared__ float shh[C * TILE];
    __shared__ float scw[C * C];
    __shared__ float smu[C], srs[C], scb[C];
    for (int i = tid; i < C * C; i += 256) scw[i] = cw[l * C * C + i];
    for (int i = tid; i < C; i += 256) {
        smu[i] = g_mu[b * C + i]; srs[i] = g_rstd[b * C + i]; scb[i] = cb[l * C + i];
    }
    for (int i = tid; i < C * TILE; i += 256) {
        int c = i / TILE, t = i % TILE; int hw = t0 + t;
        shh[i] = (hw < HW) ? g_h[src][(size_t)(b * C + c) * HW + hw] : 0.f;
    }
    __syncthreads();
    for (int i = tid; i < C * TILE; i += 256) {
        int o = i / TILE, t = i % TILE; int hw = t0 + t;
        if (hw >= HW) continue;
        float acc = scb[o];
        for (int ci = 0; ci < C; ci++) acc = fmaf(scw[o * C + ci], shh[ci * TILE + t], acc);
        float prn = (g_x1[(size_t)(b * C + o) * HW + hw] - smu[o]) * srs[o];
        g_h[src ^ 1][(size_t)(b * C + o) * HW + hw] = sinf(prn + acc);
    }
}

// ---------------- head: out = fc2( sin(fc1(h)) ) ----------------
__global__ __launch_bounds__(256) void k_head(const float* __restrict__ w1, const float* __restrict__ b1,
                                              const float* __restrict__ w2, const float* __restrict__ b2,
                                              float* __restrict__ out, int src) {
    __shared__ float sw1[128 * C];
    __shared__ float sb1[128], sw2[2 * 128];
    int tid = threadIdx.x;
    for (int i = tid; i < 128 * C; i += 256) sw1[i] = w1[i];
    for (int i = tid; i < 128; i += 256) sb1[i] = b1[i];
    for (int i = tid; i < 256; i += 256) sw2[i] = w2[i];
    __syncthreads();
    int pt = blockIdx.x * 256 + tid;               // b*HW + hw
    if (pt >= B * HW) return;
    int b = pt / HW, hw = pt % HW;
    float hv[C];
#pragma unroll
    for (int c = 0; c < C; c++) hv[c] = g_h[src][(size_t)(b * C + c) * HW + hw];
    float o0 = b2[0], o1 = b2[1];
    for (int j = 0; j < 128; j++) {
        float a = sb1[j];
#pragma unroll
        for (int c = 0; c < C; c++) a = fmaf(sw1[j * C + c], hv[c], a);
        float sv = sinf(a);
        o0 = fmaf(sw2[j], sv, o0);
        o1 = fmaf(sw2[128 + j], sv, o1);
    }
    out[pt * 2 + 0] = o0; out[pt * 2 + 1] = o1;
}

// ---------------- launcher ----------------
extern "C" void kernel_launch(void* const* d_in, const int* in_sizes, int n_in,
                              void* d_out, int out_size, void* d_ws, size_t ws_size,
                              hipStream_t stream) {
    const float* x    = (const float*)d_in[0];
    const float* fc0w = (const float*)d_in[1];
    const float* fc0b = (const float*)d_in[2];
    const float* p1   = (const float*)d_in[3];
    const float* p2   = (const float*)d_in[4];
    const float* res  = (const float*)d_in[5];
    const float* cw   = (const float*)d_in[6];
    const float* cb   = (const float*)d_in[7];
    const float* w1   = (const float*)d_in[8];
    const float* b1   = (const float*)d_in[9];
    const float* w2   = (const float*)d_in[10];
    const float* b2   = (const float*)d_in[11];
    float* out = (float*)d_out;

    k_tw<<<(H * H + W * W + 255) / 256, 256, 0, stream>>>();
    k_fc0<<<(B * C * HW + 255) / 256, 256, 0, stream>>>(x, fc0w, fc0b);
    int src = 0;
    for (int l = 0; l < NL; l++) {
        k_fft<<<B * C, 256, 0, stream>>>(src);
        k_tables<<<C * C, 256, 0, stream>>>(p1, p2, l);
        k_S<<<C * C, 256, 0, stream>>>(res, l);
        k_res1<<<B * C, 256, 0, stream>>>();
        k_ifft<<<B * C, 256, 0, stream>>>();
        k_r2<<<B * C, 256, 0, stream>>>(res, l);
        k_x2<<<B * C, 256, 0, stream>>>();
        k_comb<<<B * NTILE, 256, 0, stream>>>(cw, cb, l, src);
        src ^= 1;
    }
    k_head<<<(B * HW + 255) / 256, 256, 0, stream>>>(w1, b1, w2, b2, out, src);
}

// Round 2
// 2716.650 us; speedup vs baseline: 1.2006x; 1.2006x over previous
//
#include <hip/hip_runtime.h>
#include <math.h>

#define DI __device__ __forceinline__

constexpr int B = 16, H = 41, W = 40, C = 48, M1 = 12, M2 = 12, NL = 4;
constexpr int HW = H * W;                  // 1640
constexpr float EPS = 1e-5f;
constexpr float PI_F = 3.14159265358979323846f;

// ---------------- static device scratch (compile-time shapes) ----------------
__device__ float  g_h[2][B * C * HW];      // ping-pong activations [b][c][hw]
__device__ float2 g_alpha[B * C * HW];     // fft2(inorm(h))
__device__ float2 g_inv1[C * C * M1 * H];  // [i*C+k][p][o]
__device__ float2 g_inv2[C * C * M2 * W];  // [i*C+k][q][x]
__device__ float2 g_E1[C * C * M1 * H];    // exp(p1 * TX)  [pk][p][z]
__device__ float2 g_E2[C * C * M2 * W];    // exp(p2 * TY)  [pk][q][x]
__device__ float2 g_S[C * C * HW];         // [i*C+k][o*W+x]
__device__ float2 g_res1[B * C * HW];
__device__ float  g_x1[B * C * HW];        // pr2d output accumulator (real)
__device__ float2 g_r2[B * C * M1 * M2];
__device__ float2 g_Zr[C * C][B * M1 * M2]; // per-(i,k) res-scaled Z, reduced over i by k_r2b
__device__ float  g_mu[B * C];
__device__ float  g_rstd[B * C];
__device__ float2 g_wfh[H * H];            // e^{-2pi i o h / H}
__device__ float2 g_wfw[W * W];            // e^{-2pi i x w / W}

// ---------------- complex helpers ----------------
DI float2 cmadd(float2 a, float2 b, float2 acc) {
    acc.x = fmaf(a.x, b.x, fmaf(-a.y, b.y, acc.x));
    acc.y = fmaf(a.x, b.y, fmaf(a.y, b.x, acc.y));
    return acc;
}
DI float2 cmul(float2 a, float2 b) {
    return make_float2(a.x * b.x - a.y * b.y, a.x * b.y + a.y * b.x);
}

// ---------------- twiddle tables ----------------
__global__ void k_tw() {
    int tid = blockIdx.x * 256 + threadIdx.x;
    if (tid < H * H) {
        int o = tid / H, h = tid % H;
        float ph = -2.0f * PI_F * (float)((o * h) % H) / (float)H;
        float s, c; sincosf(ph, &s, &c);
        g_wfh[tid] = make_float2(c, s);
    }
    int t2 = tid - H * H;
    if (t2 >= 0 && t2 < W * W) {
        int o = t2 / W, w = t2 % W;
        float ph = -2.0f * PI_F * (float)((o * w) % W) / (float)W;
        float s, c; sincosf(ph, &s, &c);
        g_wfw[t2] = make_float2(c, s);
    }
}

// ---------------- fc0 + grid concat ----------------
__global__ void k_fc0(const float* __restrict__ x, const float* __restrict__ w,
                      const float* __restrict__ bias) {
    int idx = blockIdx.x * 256 + threadIdx.x;
    if (idx >= B * C * HW) return;
    int hw = idx % HW; int bc = idx / HW; int c = bc % C; int b = bc / C;
    int hh = hw / W, ww = hw % W;
    float xv = x[b * HW + hw];
    float gx = hh * (1.0f / (H - 1));
    float gy = ww * (1.0f / (W - 1));
    g_h[0][idx] = fmaf(w[c * 3 + 0], xv, fmaf(w[c * 3 + 1], gx, fmaf(w[c * 3 + 2], gy, bias[c])));
}

// ---------------- instance-norm + fft2 (per b,c) ----------------
__global__ __launch_bounds__(256) void k_fft(int src) {
    int bid = blockIdx.x;                  // b*C + c
    const float* hp = &g_h[src][(size_t)bid * HW];
    __shared__ float sh[HW];
    __shared__ float2 st[HW];
    __shared__ float red[8];
    int tid = threadIdx.x;
    float s = 0.f, ss = 0.f;
    for (int i = tid; i < HW; i += 256) { float v = hp[i]; sh[i] = v; s += v; ss += v * v; }
    for (int off = 32; off; off >>= 1) { s += __shfl_down(s, off); ss += __shfl_down(ss, off); }
    if ((tid & 63) == 0) { red[tid >> 6] = s; red[4 + (tid >> 6)] = ss; }
    __syncthreads();
    if (tid == 0) {
        float S = red[0] + red[1] + red[2] + red[3];
        float SS = red[4] + red[5] + red[6] + red[7];
        float mean = S * (1.0f / HW);
        float var = SS * (1.0f / HW) - mean * mean;
        red[0] = mean; red[1] = rsqrtf(var + EPS);
    }
    __syncthreads();
    float mean = red[0], rstd = red[1];
    for (int i = tid; i < HW; i += 256) sh[i] = (sh[i] - mean) * rstd;
    __syncthreads();
    // row DFT over h: st[o*W+w] = sum_h wfh[o,h] * sh[h,w]
    for (int i = tid; i < HW; i += 256) {
        int o = i / W, w = i % W;
        float2 acc = make_float2(0.f, 0.f);
        for (int h = 0; h < H; h++) {
            float v = sh[h * W + w];
            float2 tw = g_wfh[o * H + h];
            acc.x = fmaf(tw.x, v, acc.x); acc.y = fmaf(tw.y, v, acc.y);
        }
        st[i] = acc;
    }
    __syncthreads();
    // col DFT over w: alpha[o*W+x] = sum_w st[o,w] * wfw[x,w]
    float2* ap = &g_alpha[(size_t)bid * HW];
    for (int i = tid; i < HW; i += 256) {
        int o = i / W, x = i % W;
        float2 acc = make_float2(0.f, 0.f);
        for (int w = 0; w < W; w++) acc = cmadd(st[o * W + w], g_wfw[x * W + w], acc);
        ap[i] = acc;
    }
}

// ---------------- pole tables: inv1, inv2, E1, E2 (per i,k pair) ----------------
__global__ void k_tables(const float* __restrict__ p1, const float* __restrict__ p2, int l) {
    int pk = blockIdx.x;                   // i*C + k
    int tid = threadIdx.x;
    const float* pp1 = p1 + (size_t)(l * C * C + pk) * M1 * 2;
    const float* pp2 = p2 + (size_t)(l * C * C + pk) * M2 * 2;
    float2* inv1 = &g_inv1[(size_t)pk * M1 * H];
    float2* e1   = &g_E1[(size_t)pk * M1 * H];
    for (int i = tid; i < M1 * H; i += 256) {
        int p = i / H, o = i % H;
        float pr = pp1[p * 2], pi = pp1[p * 2 + 1];
        int ko = (o <= H / 2) ? o : o - H;           // fftfreq, H=41 odd
        float lam = (40.0f / 41.0f) * (float)ko;     // Im(LAM1)
        float a = -pr, b = lam - pi;
        float d = 1.0f / (a * a + b * b);
        inv1[i] = make_float2(a * d, -b * d);
        float t = o * (2.0f * PI_F / (H - 1));       // TX[z]
        float er = expf(pr * t);
        float sn, cs; sincosf(pi * t, &sn, &cs);
        e1[i] = make_float2(er * cs, er * sn);
    }
    float2* inv2 = &g_inv2[(size_t)pk * M2 * W];
    float2* e2   = &g_E2[(size_t)pk * M2 * W];
    for (int i = tid; i < M2 * W; i += 256) {
        int q = i / W, x = i % W;
        float pr = pp2[q * 2], pi = pp2[q * 2 + 1];
        int kx = (x < W / 2) ? x : x - W;            // fftfreq, W=40 even
        float lam = (2.0f * PI_F * 39.0f / 600.0f) * (float)kx;  // Im(LAM2)
        float a = -pr, b = lam - pi;
        float d = 1.0f / (a * a + b * b);
        inv2[i] = make_float2(a * d, -b * d);
        float t = x * (15.0f / (W - 1));             // TY[x]
        float er = expf(pr * t);
        float sn, cs; sincosf(pi * t, &sn, &cs);
        e2[i] = make_float2(er * cs, er * sn);
    }
}

// ---------------- S[i,k,o,x] = sum_p inv1[p,o] * (sum_q res[p,q] inv2[q,x]) ----------------
__global__ __launch_bounds__(256) void k_S(const float* __restrict__ res_in, int l) {
    int pk = blockIdx.x;
    int tid = threadIdx.x;
    __shared__ float2 sres[M1 * M2], sinv1[M1 * H], sinv2[M2 * W], sT[M1 * W];
    const float2* rp = (const float2*)res_in + (size_t)(l * C * C + pk) * M1 * M2;
    for (int i = tid; i < M1 * M2; i += 256) sres[i] = rp[i];
    for (int i = tid; i < M1 * H; i += 256) sinv1[i] = g_inv1[(size_t)pk * M1 * H + i];
    for (int i = tid; i < M2 * W; i += 256) sinv2[i] = g_inv2[(size_t)pk * M2 * W + i];
    __syncthreads();
    for (int i = tid; i < M1 * W; i += 256) {
        int p = i / W, x = i % W;
        float2 acc = make_float2(0.f, 0.f);
        for (int q = 0; q < M2; q++) acc = cmadd(sres[p * M2 + q], sinv2[q * W + x], acc);
        sT[i] = acc;
    }
    __syncthreads();
    float2* sp = &g_S[(size_t)pk * HW];
    for (int i = tid; i < HW; i += 256) {
        int o = i / W, x = i % W;
        float2 acc = make_float2(0.f, 0.f);
        for (int p = 0; p < M1; p++) acc = cmadd(sinv1[p * H + o], sT[p * W + x], acc);
        sp[i] = acc;
    }
}

// ---------------- res1[b,k,ox] = sum_i alpha[b,i,ox] * S[i,k,ox] ----------------
__global__ __launch_bounds__(256) void k_res1() {
    int bid = blockIdx.x; int k = bid % C, b = bid / C;
    int tid = threadIdx.x;
    float2 acc[7];
#pragma unroll
    for (int j = 0; j < 7; j++) acc[j] = make_float2(0.f, 0.f);
    for (int i = 0; i < C; i++) {
        const float2* ap = &g_alpha[(size_t)(b * C + i) * HW];
        const float2* sp = &g_S[(size_t)(i * C + k) * HW];
#pragma unroll
        for (int j = 0; j < 7; j++) {
            int idx = tid + j * 256;
            if (idx < HW) acc[j] = cmadd(ap[idx], sp[idx], acc[j]);
        }
    }
    float2* rp = &g_res1[(size_t)bid * HW];
#pragma unroll
    for (int j = 0; j < 7; j++) { int idx = tid + j * 256; if (idx < HW) rp[idx] = acc[j]; }
}

// ---------------- x1 = ifft2(res1).real ----------------
__global__ __launch_bounds__(256) void k_ifft() {
    int bid = blockIdx.x; int tid = threadIdx.x;
    __shared__ float2 s0[HW], s1[HW];
    const float2* rp = &g_res1[(size_t)bid * HW];
    for (int i = tid; i < HW; i += 256) s0[i] = rp[i];
    __syncthreads();
    // inverse over o: s1[h,x] = sum_o s0[o,x] * conj(wfh[o,h])
    for (int i = tid; i < HW; i += 256) {
        int h = i / W, x = i % W;
        float2 acc = make_float2(0.f, 0.f);
        for (int o = 0; o < H; o++) {
            float2 v = s0[o * W + x]; float2 tw = g_wfh[o * H + h];
            acc.x = fmaf(v.x, tw.x, fmaf(v.y, tw.y, acc.x));
            acc.y = fmaf(v.y, tw.x, fmaf(-v.x, tw.y, acc.y));
        }
        s1[i] = acc;
    }
    __syncthreads();
    float* xp = &g_x1[(size_t)bid * HW];
    for (int i = tid; i < HW; i += 256) {
        int h = i / W, w = i % W;
        float acc = 0.f;
        for (int x = 0; x < W; x++) {
            float2 v = s1[h * W + x]; float2 tw = g_wfw[x * W + w];
            acc = fmaf(v.x, tw.x, fmaf(v.y, tw.y, acc));  // Re(v * conj(tw))
        }
        xp[i] = acc * (1.0f / (H * W));
    }
}

// ---------------- k_r2a: per (i,k): Z[b,p,q] = inv1 @ alpha[b,i] @ inv2^T, scaled by res ---
// thread layout Y phase: t = bt*80 + ph*40 + x (t<240); 6 p-accumulators per thread.
// Z phase: t = b*12+p (t<192); 12 q-accumulators.
__global__ __launch_bounds__(256) void k_r2a(const float* __restrict__ res_in, int l) {
    int pk = blockIdx.x;                   // i*C + k
    int i = pk / C;
    int tid = threadIdx.x;
    __shared__ float2 sY[B * M1 * 41];     // [(b*12+p)*41 + x]   62.9 KB
    __shared__ float2 si1t[H * 16];        // transposed inv1 [o][p] (pad 16)
    __shared__ float2 si2[M2 * 41];        // [q*41 + x]
    __shared__ float2 sres[M1 * M2];
    // table loads
    for (int idx = tid; idx < M1 * H; idx += 256) {
        int p = idx / H, o = idx % H;
        si1t[o * 16 + p] = g_inv1[(size_t)pk * M1 * H + idx];
    }
    for (int idx = tid; idx < M2 * W; idx += 256) {
        int q = idx / W, x = idx % W;
        si2[q * 41 + x] = g_inv2[(size_t)pk * M2 * W + idx];
    }
    const float2* rp = (const float2*)res_in + (size_t)(l * C * C + pk) * M1 * M2;
    for (int idx = tid; idx < M1 * M2; idx += 256) sres[idx] = rp[idx];
    __syncthreads();
    // ---- Y phase ----
    if (tid < 240) {
        int bt = tid / 80, rem = tid % 80;
        int ph = rem / 40, x = rem % 40;
        int p0 = ph * 6;
        for (int b = bt; b < B; b += 3) {
            const float2* ap = &g_alpha[(size_t)(b * C + i) * HW + x];
            float2 yacc[6];
#pragma unroll
            for (int pp = 0; pp < 6; pp++) yacc[pp] = make_float2(0.f, 0.f);
            for (int o = 0; o < H; o++) {
                float2 a = ap[o * W];
                const float2* e = &si1t[o * 16 + p0];
#pragma unroll
                for (int pp = 0; pp < 6; pp++) yacc[pp] = cmadd(e[pp], a, yacc[pp]);
            }
#pragma unroll
            for (int pp = 0; pp < 6; pp++) sY[(b * M1 + p0 + pp) * 41 + x] = yacc[pp];
        }
    }
    __syncthreads();
    // ---- Z phase ----
    if (tid < 192) {
        int b = tid / 12, p = tid % 12;
        float2 zacc[12];
#pragma unroll
        for (int q = 0; q < 12; q++) zacc[q] = make_float2(0.f, 0.f);
        const float2* yrow = &sY[(b * M1 + p) * 41];
        for (int x = 0; x < W; x++) {
            float2 y = yrow[x];
#pragma unroll
            for (int q = 0; q < 12; q++) zacc[q] = cmadd(y, si2[q * 41 + x], zacc[q]);
        }
        float2* out = &g_Zr[pk][b * (M1 * M2) + p * M2];
#pragma unroll
        for (int q = 0; q < 12; q++) out[q] = cmul(sres[p * M2 + q], zacc[q]);
    }
}

// ---------------- k_r2b: r2[b,k,p,q] = sum_i Zr[i*C+k][b,p,q] ----------------
__global__ __launch_bounds__(256) void k_r2b() {
    int t = blockIdx.x * 256 + threadIdx.x;        // < B*C*144
    if (t >= B * C * M1 * M2) return;
    int pq = t % (M1 * M2);
    int k = (t / (M1 * M2)) % C;
    int b = t / (M1 * M2 * C);
    float2 acc = make_float2(0.f, 0.f);
    for (int i = 0; i < C; i++) {
        float2 v = g_Zr[i * C + k][b * (M1 * M2) + pq];
        acc.x += v.x; acc.y += v.y;
    }
    g_r2[(size_t)(b * C + k) * (M1 * M2) + pq] = acc;
}

// ---------------- k_x2: x2 += Re(E1^T r2 E2) summed over ci; finalize pr + stats ----------
constexpr int XNCI = 4;
__global__ __launch_bounds__(256) void k_x2() {
    int bid = blockIdx.x; int k = bid % C, b = bid / C;
    int tid = threadIdx.x;
    __shared__ float2 sE1[XNCI * M1 * 42];   // [jp][z] rows padded to 42 (b128-aligned)
    __shared__ float2 sV [XNCI * M1 * 42];   // [jp][x] rows padded to 42
    __shared__ float2 sE2[XNCI * M2 * 41];   // [j][q][x] rows padded to 41
    __shared__ float2 sr2[XNCI * M1 * M2];
    __shared__ float red[8];
    // accr register tile: 2z x 4x per thread (tid < 210)
    int zg = tid / 10, xg = tid % 10;
    int z0 = zg * 2, x0 = xg * 4;
    float accr[2][4];
#pragma unroll
    for (int zi = 0; zi < 2; zi++)
#pragma unroll
        for (int xi = 0; xi < 4; xi++) accr[zi][xi] = 0.f;

    for (int cg = 0; cg < C / XNCI; cg++) {
        // table loads for ci = cg*XNCI + j
        for (int idx = tid; idx < XNCI * M1 * H; idx += 256) {
            int j = idx / (M1 * H), rem = idx % (M1 * H);
            int p = rem / H, z = rem % H;
            sE1[(j * M1 + p) * 42 + z] = g_E1[(size_t)((cg * XNCI + j) * C + k) * (M1 * H) + rem];
        }
        for (int idx = tid; idx < XNCI * M2 * W; idx += 256) {
            int j = idx / (M2 * W), rem = idx % (M2 * W);
            int q = rem / W, x = rem % W;
            sE2[(j * M2 + q) * 41 + x] = g_E2[(size_t)((cg * XNCI + j) * C + k) * (M2 * W) + rem];
        }
        for (int idx = tid; idx < XNCI * M1 * M2; idx += 256) {
            int j = idx / (M1 * M2);
            sr2[idx] = g_r2[(size_t)(b * C + cg * XNCI + j) * (M1 * M2) + (idx % (M1 * M2))];
        }
        __syncthreads();
        // V phase: V[j,p,x] = sum_q r2[j][p,q] * E2[j][q,x]    (XNCI*480 items)
        for (int r = 0; r < 8; r++) {
            int id = tid + r * 256;
            if (id < XNCI * M1 * W) {
                int j = id / (M1 * W), rem = id % (M1 * W);
                int p = rem / W, x = rem % W;
                float2 a = make_float2(0.f, 0.f);
#pragma unroll
                for (int q = 0; q < M2; q++)
                    a = cmadd(sr2[j * (M1 * M2) + p * M2 + q], sE2[(j * M2 + q) * 41 + x], a);
                sV[(j * M1 + p) * 42 + x] = a;
            }
        }
        __syncthreads();
        // accr phase: accr[z,x] += Re( E1[jp][z] * V[jp][x] ), jp over XNCI*12
        if (tid < 210) {
            for (int jp = 0; jp < XNCI * M1; jp++) {
                const float4* ep = (const float4*)&sE1[jp * 42 + z0];
                float4 e = *ep;                      // (Re z0, Im z0, Re z1, Im z1)
                const float4* vp = (const float4*)&sV[jp * 42 + x0];
                float4 v01 = vp[0], v23 = vp[1];
                accr[0][0] = fmaf(e.x, v01.x, fmaf(-e.y, v01.y, accr[0][0]));
                accr[0][1] = fmaf(e.x, v01.z, fmaf(-e.y, v01.w, accr[0][1]));
                accr[0][2] = fmaf(e.x, v23.x, fmaf(-e.y, v23.y, accr[0][2]));
                accr[0][3] = fmaf(e.x, v23.z, fmaf(-e.y, v23.w, accr[0][3]));
                accr[1][0] = fmaf(e.z, v01.x, fmaf(-e.w, v01.y, accr[1][0]));
                accr[1][1] = fmaf(e.z, v01.z, fmaf(-e.w, v01.w, accr[1][1]));
                accr[1][2] = fmaf(e.z, v23.x, fmaf(-e.w, v23.y, accr[1][2]));
                accr[1][3] = fmaf(e.z, v23.z, fmaf(-e.w, v23.w, accr[1][3]));
            }
        }
        __syncthreads();
    }
    // finalize: pr = x1 + x2/(H*W); write back; stats
    float* xp = &g_x1[(size_t)bid * HW];
    float s = 0.f, ss = 0.f;
    if (tid < 210) {
#pragma unroll
        for (int zi = 0; zi < 2; zi++) {
            int z = z0 + zi;
            if (z < H) {
#pragma unroll
                for (int xi = 0; xi < 4; xi++) {
                    int idx = z * W + x0 + xi;
                    float v = xp[idx] + accr[zi][xi] * (1.0f / (H * W));
                    xp[idx] = v; s += v; ss += v * v;
                }
            }
        }
    }
    for (int off = 32; off; off >>= 1) { s += __shfl_down(s, off); ss += __shfl_down(ss, off); }
    if ((tid & 63) == 0) { red[tid >> 6] = s; red[4 + (tid >> 6)] = ss; }
    __syncthreads();
    if (tid == 0) {
        float S = red[0] + red[1] + red[2] + red[3];
        float SS = red[4] + red[5] + red[6] + red[7];
        float mean = S * (1.0f / HW);
        float var = SS * (1.0f / HW) - mean * mean;
        g_mu[bid] = mean; g_rstd[bid] = rsqrtf(var + EPS);
    }
}

// ---------------- h_next = sin( inorm(pr) + conv(h) + conv_b ) ----------------
constexpr int TILE = 128;
constexpr int NTILE = (HW + TILE - 1) / TILE;   // 13
__global__ __launch_bounds__(256) void k_comb(const float* __restrict__ cw,
                                              const float* __restrict__ cb, int l, int src) {
    int b = blockIdx.x / NTILE;
    int t0 = (blockIdx.x % NTILE) * TILE;
    int tid = threadIdx.x;
    __shared__ float shh[C * TILE];
    __shared__ float scw[C * C];
    __shared__ float smu[C], srs[C], scb[C];
    for (int i = tid; i < C * C; i += 256) scw[i] = cw[l * C * C + i];
    for (int i = tid; i < C; i += 256) {
        smu[i] = g_mu[b * C + i]; srs[i] = g_rstd[b * C + i]; scb[i] = cb[l * C + i];
    }
    for (int i = tid; i < C * TILE; i += 256) {
        int c = i / TILE, t = i % TILE; int hw = t0 + t;
        shh[i] = (hw < HW) ? g_h[src][(size_t)(b * C + c) * HW + hw] : 0.f;
    }
    __syncthreads();
    for (int i = tid; i < C * TILE; i += 256) {
        int o = i / TILE, t = i % TILE; int hw = t0 + t;
        if (hw >= HW) continue;
        float acc = scb[o];
        for (int ci = 0; ci < C; ci++) acc = fmaf(scw[o * C + ci], shh[ci * TILE + t], acc);
        float prn = (g_x1[(size_t)(b * C + o) * HW + hw] - smu[o]) * srs[o];
        g_h[src ^ 1][(size_t)(b * C + o) * HW + hw] = sinf(prn + acc);
    }
}

// ---------------- head: out = fc2( sin(fc1(h)) ) ----------------
__global__ __launch_bounds__(256) void k_head(const float* __restrict__ w1, const float* __restrict__ b1,
                                              const float* __restrict__ w2, const float* __restrict__ b2,
                                              float* __restrict__ out, int src) {
    __shared__ float sw1[128 * C];
    __shared__ float sb1[128], sw2[2 * 128];
    int tid = threadIdx.x;
    for (int i = tid; i < 128 * C; i += 256) sw1[i] = w1[i];
    for (int i = tid; i < 128; i += 256) sb1[i] = b1[i];
    for (int i = tid; i < 256; i += 256) sw2[i] = w2[i];
    __syncthreads();
    int pt = blockIdx.x * 256 + tid;               // b*HW + hw
    if (pt >= B * HW) return;
    int b = pt / HW, hw = pt % HW;
    float hv[C];
#pragma unroll
    for (int c = 0; c < C; c++) hv[c] = g_h[src][(size_t)(b * C + c) * HW + hw];
    float o0 = b2[0], o1 = b2[1];
    for (int j = 0; j < 128; j++) {
        float a = sb1[j];
#pragma unroll
        for (int c = 0; c < C; c++) a = fmaf(sw1[j * C + c], hv[c], a);
        float sv = sinf(a);
        o0 = fmaf(sw2[j], sv, o0);
        o1 = fmaf(sw2[128 + j], sv, o1);
    }
    out[pt * 2 + 0] = o0; out[pt * 2 + 1] = o1;
}

// ---------------- launcher ----------------
extern "C" void kernel_launch(void* const* d_in, const int* in_sizes, int n_in,
                              void* d_out, int out_size, void* d_ws, size_t ws_size,
                              hipStream_t stream) {
    const float* x    = (const float*)d_in[0];
    const float* fc0w = (const float*)d_in[1];
    const float* fc0b = (const float*)d_in[2];
    const float* p1   = (const float*)d_in[3];
    const float* p2   = (const float*)d_in[4];
    const float* res  = (const float*)d_in[5];
    const float* cw   = (const float*)d_in[6];
    const float* cb   = (const float*)d_in[7];
    const float* w1   = (const float*)d_in[8];
    const float* b1   = (const float*)d_in[9];
    const float* w2   = (const float*)d_in[10];
    const float* b2   = (const float*)d_in[11];
    float* out = (float*)d_out;

    k_tw<<<(H * H + W * W + 255) / 256, 256, 0, stream>>>();
    k_fc0<<<(B * C * HW + 255) / 256, 256, 0, stream>>>(x, fc0w, fc0b);
    int src = 0;
    for (int l = 0; l < NL; l++) {
        k_fft<<<B * C, 256, 0, stream>>>(src);
        k_tables<<<C * C, 256, 0, stream>>>(p1, p2, l);
        k_S<<<C * C, 256, 0, stream>>>(res, l);
        k_res1<<<B * C, 256, 0, stream>>>();
        k_ifft<<<B * C, 256, 0, stream>>>();
        k_r2a<<<C * C, 256, 0, stream>>>(res, l);
        k_r2b<<<(B * C * M1 * M2 + 255) / 256, 256, 0, stream>>>();
        k_x2<<<B * C, 256, 0, stream>>>();
        k_comb<<<B * NTILE, 256, 0, stream>>>(cw, cb, l, src);
        src ^= 1;
    }
    k_head<<<(B * HW + 255) / 256, 256, 0, stream>>>(w1, b1, w2, b2, out, src);
}

// Round 3
// 2205.766 us; speedup vs baseline: 1.4787x; 1.2316x over previous
//
#include <hip/hip_runtime.h>
#include <math.h>

#define DI __device__ __forceinline__

constexpr int B = 16, H = 41, W = 40, C = 48, M1 = 12, M2 = 12, NL = 4;
constexpr int HW = H * W;                  // 1640
constexpr float EPS = 1e-5f;
constexpr float PI_F = 3.14159265358979323846f;

// ---------------- static device scratch (compile-time shapes) ----------------
__device__ float  g_h[2][B * C * HW];      // ping-pong activations [b][c][hw]
__device__ float2 g_alpha[B * C * HW];     // fft2(inorm(h))
__device__ float2 g_inv1[C * C * M1 * H];  // [i*C+k][p][o]
__device__ float2 g_inv2[C * C * M2 * W];  // [i*C+k][q][x]
__device__ float2 g_E1[C * C * M1 * H];    // exp(p1 * TX)  [pk][p][z]
__device__ float2 g_E2[C * C * M2 * W];    // exp(p2 * TY)  [pk][q][x]
__device__ float2 g_S[C * C * HW];         // [i*C+k][o*W+x]
__device__ float2 g_res1[B * C * HW];
__device__ float  g_x1[B * C * HW];        // pr2d output accumulator (real)
__device__ float2 g_r2[B * C * M1 * M2];
__device__ float2 g_Zr[C * C][B * M1 * M2]; // per-(i,k) res-scaled Z, reduced over i by k_r2b
__device__ float  g_mu[B * C];
__device__ float  g_rstd[B * C];
__device__ float2 g_wfh[H * H];            // e^{-2pi i o h / H}
__device__ float2 g_wfw[W * W];            // e^{-2pi i x w / W}

// ---------------- complex helpers ----------------
DI float2 cmadd(float2 a, float2 b, float2 acc) {
    acc.x = fmaf(a.x, b.x, fmaf(-a.y, b.y, acc.x));
    acc.y = fmaf(a.x, b.y, fmaf(a.y, b.x, acc.y));
    return acc;
}
DI float2 cmul(float2 a, float2 b) {
    return make_float2(a.x * b.x - a.y * b.y, a.x * b.y + a.y * b.x);
}

// ---------------- twiddle tables ----------------
__global__ void k_tw() {
    int tid = blockIdx.x * 256 + threadIdx.x;
    if (tid < H * H) {
        int o = tid / H, h = tid % H;
        float ph = -2.0f * PI_F * (float)((o * h) % H) / (float)H;
        float s, c; sincosf(ph, &s, &c);
        g_wfh[tid] = make_float2(c, s);
    }
    int t2 = tid - H * H;
    if (t2 >= 0 && t2 < W * W) {
        int o = t2 / W, w = t2 % W;
        float ph = -2.0f * PI_F * (float)((o * w) % W) / (float)W;
        float s, c; sincosf(ph, &s, &c);
        g_wfw[t2] = make_float2(c, s);
    }
}

// ---------------- fc0 + grid concat ----------------
__global__ void k_fc0(const float* __restrict__ x, const float* __restrict__ w,
                      const float* __restrict__ bias) {
    int idx = blockIdx.x * 256 + threadIdx.x;
    if (idx >= B * C * HW) return;
    int hw = idx % HW; int bc = idx / HW; int c = bc % C; int b = bc / C;
    int hh = hw / W, ww = hw % W;
    float xv = x[b * HW + hw];
    float gx = hh * (1.0f / (H - 1));
    float gy = ww * (1.0f / (W - 1));
    g_h[0][idx] = fmaf(w[c * 3 + 0], xv, fmaf(w[c * 3 + 1], gx, fmaf(w[c * 3 + 2], gy, bias[c])));
}

// ---------------- instance-norm + fft2 (per b,c) ----------------
__global__ __launch_bounds__(256) void k_fft(int src) {
    int bid = blockIdx.x;                  // b*C + c
    const float* hp = &g_h[src][(size_t)bid * HW];
    __shared__ float sh[HW];
    __shared__ float2 st[HW];
    __shared__ float red[8];
    int tid = threadIdx.x;
    float s = 0.f, ss = 0.f;
    for (int i = tid; i < HW; i += 256) { float v = hp[i]; sh[i] = v; s += v; ss += v * v; }
    for (int off = 32; off; off >>= 1) { s += __shfl_down(s, off); ss += __shfl_down(ss, off); }
    if ((tid & 63) == 0) { red[tid >> 6] = s; red[4 + (tid >> 6)] = ss; }
    __syncthreads();
    if (tid == 0) {
        float S = red[0] + red[1] + red[2] + red[3];
        float SS = red[4] + red[5] + red[6] + red[7];
        float mean = S * (1.0f / HW);
        float var = SS * (1.0f / HW) - mean * mean;
        red[0] = mean; red[1] = rsqrtf(var + EPS);
    }
    __syncthreads();
    float mean = red[0], rstd = red[1];
    for (int i = tid; i < HW; i += 256) sh[i] = (sh[i] - mean) * rstd;
    __syncthreads();
    // row DFT over h: st[o*W+w] = sum_h wfh[o,h] * sh[h,w]
    for (int i = tid; i < HW; i += 256) {
        int o = i / W, w = i % W;
        float2 acc = make_float2(0.f, 0.f);
        for (int h = 0; h < H; h++) {
            float v = sh[h * W + w];
            float2 tw = g_wfh[o * H + h];
            acc.x = fmaf(tw.x, v, acc.x); acc.y = fmaf(tw.y, v, acc.y);
        }
        st[i] = acc;
    }
    __syncthreads();
    // col DFT over w: alpha[o*W+x] = sum_w st[o,w] * wfw[x,w]
    float2* ap = &g_alpha[(size_t)bid * HW];
    for (int i = tid; i < HW; i += 256) {
        int o = i / W, x = i % W;
        float2 acc = make_float2(0.f, 0.f);
        for (int w = 0; w < W; w++) acc = cmadd(st[o * W + w], g_wfw[x * W + w], acc);
        ap[i] = acc;
    }
}

// ---------------- pole tables: inv1, inv2, E1, E2 (per i,k pair) ----------------
__global__ void k_tables(const float* __restrict__ p1, const float* __restrict__ p2, int l) {
    int pk = blockIdx.x;                   // i*C + k
    int tid = threadIdx.x;
    const float* pp1 = p1 + (size_t)(l * C * C + pk) * M1 * 2;
    const float* pp2 = p2 + (size_t)(l * C * C + pk) * M2 * 2;
    float2* inv1 = &g_inv1[(size_t)pk * M1 * H];
    float2* e1   = &g_E1[(size_t)pk * M1 * H];
    for (int i = tid; i < M1 * H; i += 256) {
        int p = i / H, o = i % H;
        float pr = pp1[p * 2], pi = pp1[p * 2 + 1];
        int ko = (o <= H / 2) ? o : o - H;           // fftfreq, H=41 odd
        float lam = (40.0f / 41.0f) * (float)ko;     // Im(LAM1)
        float a = -pr, b = lam - pi;
        float d = 1.0f / (a * a + b * b);
        inv1[i] = make_float2(a * d, -b * d);
        float t = o * (2.0f * PI_F / (H - 1));       // TX[z]
        float er = expf(pr * t);
        float sn, cs; sincosf(pi * t, &sn, &cs);
        e1[i] = make_float2(er * cs, er * sn);
    }
    float2* inv2 = &g_inv2[(size_t)pk * M2 * W];
    float2* e2   = &g_E2[(size_t)pk * M2 * W];
    for (int i = tid; i < M2 * W; i += 256) {
        int q = i / W, x = i % W;
        float pr = pp2[q * 2], pi = pp2[q * 2 + 1];
        int kx = (x < W / 2) ? x : x - W;            // fftfreq, W=40 even
        float lam = (2.0f * PI_F * 39.0f / 600.0f) * (float)kx;  // Im(LAM2)
        float a = -pr, b = lam - pi;
        float d = 1.0f / (a * a + b * b);
        inv2[i] = make_float2(a * d, -b * d);
        float t = x * (15.0f / (W - 1));             // TY[x]
        float er = expf(pr * t);
        float sn, cs; sincosf(pi * t, &sn, &cs);
        e2[i] = make_float2(er * cs, er * sn);
    }
}

// ---------------- S[i,k,o,x] = sum_p inv1[p,o] * (sum_q res[p,q] inv2[q,x]) ----------------
__global__ __launch_bounds__(256) void k_S(const float* __restrict__ res_in, int l) {
    int pk = blockIdx.x;
    int tid = threadIdx.x;
    __shared__ float2 sres[M1 * M2], sinv1[M1 * H], sinv2[M2 * W], sT[M1 * W];
    const float2* rp = (const float2*)res_in + (size_t)(l * C * C + pk) * M1 * M2;
    for (int i = tid; i < M1 * M2; i += 256) sres[i] = rp[i];
    for (int i = tid; i < M1 * H; i += 256) sinv1[i] = g_inv1[(size_t)pk * M1 * H + i];
    for (int i = tid; i < M2 * W; i += 256) sinv2[i] = g_inv2[(size_t)pk * M2 * W + i];
    __syncthreads();
    for (int i = tid; i < M1 * W; i += 256) {
        int p = i / W, x = i % W;
        float2 acc = make_float2(0.f, 0.f);
        for (int q = 0; q < M2; q++) acc = cmadd(sres[p * M2 + q], sinv2[q * W + x], acc);
        sT[i] = acc;
    }
    __syncthreads();
    float2* sp = &g_S[(size_t)pk * HW];
    for (int i = tid; i < HW; i += 256) {
        int o = i / W, x = i % W;
        float2 acc = make_float2(0.f, 0.f);
        for (int p = 0; p < M1; p++) acc = cmadd(sinv1[p * H + o], sT[p * W + x], acc);
        sp[i] = acc;
    }
}

// ---------------- res1[b,k,ox] = sum_i alpha[b,i,ox] * S[i,k,ox] ----------------
__global__ __launch_bounds__(256) void k_res1() {
    // XCD-aware remap: same-k blocks cluster on one XCD (S k-slice L2-resident)
    int bid = blockIdx.x;
    int xcd = bid & 7, idx = bid >> 3;             // idx 0..95
    int k = (idx / B) * 8 + xcd;
    int b = idx % B;
    int tid = threadIdx.x;
    float2 acc[7];
#pragma unroll
    for (int j = 0; j < 7; j++) acc[j] = make_float2(0.f, 0.f);
    for (int i = 0; i < C; i++) {
        const float2* ap = &g_alpha[(size_t)(b * C + i) * HW];
        const float2* sp = &g_S[(size_t)(i * C + k) * HW];
#pragma unroll
        for (int j = 0; j < 7; j++) {
            int idx2 = tid + j * 256;
            if (idx2 < HW) acc[j] = cmadd(ap[idx2], sp[idx2], acc[j]);
        }
    }
    float2* rp = &g_res1[(size_t)(b * C + k) * HW];
#pragma unroll
    for (int j = 0; j < 7; j++) { int idx2 = tid + j * 256; if (idx2 < HW) rp[idx2] = acc[j]; }
}

// ---------------- x1 = ifft2(res1).real ----------------
__global__ __launch_bounds__(256) void k_ifft() {
    int bid = blockIdx.x; int tid = threadIdx.x;
    __shared__ float2 s0[HW], s1[HW];
    const float2* rp = &g_res1[(size_t)bid * HW];
    for (int i = tid; i < HW; i += 256) s0[i] = rp[i];
    __syncthreads();
    // inverse over o: s1[h,x] = sum_o s0[o,x] * conj(wfh[o,h])
    for (int i = tid; i < HW; i += 256) {
        int h = i / W, x = i % W;
        float2 acc = make_float2(0.f, 0.f);
        for (int o = 0; o < H; o++) {
            float2 v = s0[o * W + x]; float2 tw = g_wfh[o * H + h];
            acc.x = fmaf(v.x, tw.x, fmaf(v.y, tw.y, acc.x));
            acc.y = fmaf(v.y, tw.x, fmaf(-v.x, tw.y, acc.y));
        }
        s1[i] = acc;
    }
    __syncthreads();
    float* xp = &g_x1[(size_t)bid * HW];
    for (int i = tid; i < HW; i += 256) {
        int h = i / W, w = i % W;
        float acc = 0.f;
        for (int x = 0; x < W; x++) {
            float2 v = s1[h * W + x]; float2 tw = g_wfw[x * W + w];
            acc = fmaf(v.x, tw.x, fmaf(v.y, tw.y, acc));  // Re(v * conj(tw))
        }
        xp[i] = acc * (1.0f / (H * W));
    }
}

// ---------------- k_r2a v2: per (i,k): Zr[b,p,q] = res ⊙ (inv1 @ alpha[b,i] @ inv2^T) ------
// b processed in 4 chunks of 4. LDS ~26KB -> 6 blocks/CU.
// Y phase: 160 thr = (bloc4 x x40), 12 p-accumulators each.
// Z phase: 192 thr = (bloc4 x p12 x qq4), 3 q-accumulators each.
__global__ __launch_bounds__(256) void k_r2a(const float* __restrict__ res_in, int l) {
    // XCD-aware remap: same-i blocks on one XCD (alpha[:,i] slices L2-resident)
    int bid = blockIdx.x;
    int xcd = bid & 7, idx = bid >> 3;             // idx 0..287
    int i = (idx / C) * 8 + xcd;                   // 6 i's per XCD
    int k = idx % C;
    int pk = i * C + k;
    int tid = threadIdx.x;
    __shared__ float2 sY[4 * M1 * 41];             // 15.7 KB
    __shared__ float2 si1t[H * 16];                // transposed inv1 [o][p]
    __shared__ float2 si2[M2 * 41];                // [q*41 + x]
    __shared__ float2 sres[M1 * M2];
    for (int t = tid; t < M1 * H; t += 256) {
        int p = t / H, o = t % H;
        si1t[o * 16 + p] = g_inv1[(size_t)pk * M1 * H + t];
    }
    for (int t = tid; t < M2 * W; t += 256) {
        int q = t / W, x = t % W;
        si2[q * 41 + x] = g_inv2[(size_t)pk * M2 * W + t];
    }
    const float2* rp = (const float2*)res_in + (size_t)(l * C * C + pk) * M1 * M2;
    for (int t = tid; t < M1 * M2; t += 256) sres[t] = rp[t];
    __syncthreads();
    for (int c = 0; c < 4; c++) {
        if (c > 0) __syncthreads();                // prev Z done before sY overwrite
        if (tid < 160) {
            int bloc = tid / 40, x = tid % 40;
            int b = c * 4 + bloc;
            const float2* ap = &g_alpha[(size_t)(b * C + i) * HW + x];
            float2 yacc[12];
#pragma unroll
            for (int p = 0; p < 12; p++) yacc[p] = make_float2(0.f, 0.f);
            for (int o = 0; o < H; o++) {
                float2 a = ap[o * W];
                const float2* e = &si1t[o * 16];
#pragma unroll
                for (int p = 0; p < 12; p++) yacc[p] = cmadd(e[p], a, yacc[p]);
            }
#pragma unroll
            for (int p = 0; p < 12; p++) sY[(bloc * M1 + p) * 41 + x] = yacc[p];
        }
        __syncthreads();
        if (tid < 192) {
            int bloc = tid / 48, rem = tid % 48;
            int p = rem >> 2, qq = rem & 3;
            int q0 = qq * 3;
            float2 zacc[3];
#pragma unroll
            for (int j = 0; j < 3; j++) zacc[j] = make_float2(0.f, 0.f);
            const float2* yrow = &sY[(bloc * M1 + p) * 41];
            for (int x = 0; x < W; x++) {
                float2 y = yrow[x];
#pragma unroll
                for (int j = 0; j < 3; j++) zacc[j] = cmadd(y, si2[(q0 + j) * 41 + x], zacc[j]);
            }
            int b = c * 4 + bloc;
            float2* out = &g_Zr[pk][b * (M1 * M2) + p * M2 + q0];
#pragma unroll
            for (int j = 0; j < 3; j++) out[j] = cmul(sres[p * M2 + q0 + j], zacc[j]);
        }
    }
}

// ---------------- k_r2b: r2[b,k,p,q] = sum_i Zr[i*C+k][b,p,q] ----------------
__global__ __launch_bounds__(256) void k_r2b() {
    int t = blockIdx.x * 256 + threadIdx.x;        // < B*C*144
    if (t >= B * C * M1 * M2) return;
    int pq = t % (M1 * M2);
    int k = (t / (M1 * M2)) % C;
    int b = t / (M1 * M2 * C);
    float2 acc = make_float2(0.f, 0.f);
    for (int i = 0; i < C; i++) {
        float2 v = g_Zr[i * C + k][b * (M1 * M2) + pq];
        acc.x += v.x; acc.y += v.y;
    }
    g_r2[(size_t)(b * C + k) * (M1 * M2) + pq] = acc;
}

// ---------------- k_x2 v2: x2 += Re(E1^T r2 E2) over ci; finalize pr + stats ----------
// XNCI=2 (LDS ~26KB -> 6 blocks/CU). accr: x-as-lane (thread = 2x * 4z), rows:
// sV stride 40, sE1 stride 44 (zero-padded) -> low-conflict float4 reads.
constexpr int XNCI = 2;
__global__ __launch_bounds__(256) void k_x2() {
    // XCD-aware remap: same-k blocks on one XCD (E1/E2 k-slices L2-resident)
    int bid = blockIdx.x;
    int xcd = bid & 7, idx = bid >> 3;             // 0..95
    int k = (idx / B) * 8 + xcd;
    int b = idx % B;
    int tid = threadIdx.x;
    __shared__ float2 sE1[XNCI * M1 * 44];         // [jp][z], z-padded to 44 (zeros)
    __shared__ float2 sV [XNCI * M1 * 40];         // [jp][x]
    __shared__ float2 sE2[XNCI * M2 * 41];         // [jq][x]
    __shared__ float2 sr2[XNCI * M1 * M2];
    __shared__ float red[8];
    int xh = tid % 20, zq = tid / 20;              // active: tid<240
    int x0 = xh * 2, z0 = zq * 4;
    float accr[4][2];
#pragma unroll
    for (int zi = 0; zi < 4; zi++) { accr[zi][0] = 0.f; accr[zi][1] = 0.f; }

    for (int cg = 0; cg < C / XNCI; cg++) {
        for (int t = tid; t < XNCI * M1 * 44; t += 256) {
            int j = t / (M1 * 44), rem = t % (M1 * 44);
            int p = rem / 44, z = rem % 44;
            sE1[t] = (z < H) ? g_E1[(size_t)((cg * XNCI + j) * C + k) * (M1 * H) + p * H + z]
                             : make_float2(0.f, 0.f);
        }
        for (int t = tid; t < XNCI * M2 * W; t += 256) {
            int j = t / (M2 * W), rem = t % (M2 * W);
            sE2[(t / W) * 41 + (t % W)] = g_E2[(size_t)((cg * XNCI + j) * C + k) * (M2 * W) + rem];
        }
        for (int t = tid; t < XNCI * M1 * M2; t += 256) {
            int j = t / (M1 * M2);
            sr2[t] = g_r2[(size_t)(b * C + cg * XNCI + j) * (M1 * M2) + (t % (M1 * M2))];
        }
        __syncthreads();
        // V[jp][x] = sum_q r2[j][p,q] * E2[j][q,x]   (XNCI*480 = 960 items)
        for (int r = 0; r < 4; r++) {
            int id = tid + r * 256;
            if (id < XNCI * M1 * W) {
                int j = id / (M1 * W), rem = id % (M1 * W);
                int p = rem / W, x = rem % W;
                float2 a = make_float2(0.f, 0.f);
#pragma unroll
                for (int q = 0; q < M2; q++)
                    a = cmadd(sr2[j * (M1 * M2) + p * M2 + q], sE2[(j * M2 + q) * 41 + x], a);
                sV[(j * M1 + p) * 40 + x] = a;
            }
        }
        __syncthreads();
        // accr[z,x] += Re( E1[jp][z] * V[jp][x] )
        if (tid < 240 && z0 < H) {
            for (int jp = 0; jp < XNCI * M1; jp++) {
                float4 v  = *(const float4*)&sV[jp * 40 + x0];        // x0, x0+1
                float4 eA = *(const float4*)&sE1[jp * 44 + z0];       // z0, z0+1
                float4 eB = *(const float4*)&sE1[jp * 44 + z0 + 2];   // z0+2, z0+3
                accr[0][0] = fmaf(eA.x, v.x, fmaf(-eA.y, v.y, accr[0][0]));
                accr[0][1] = fmaf(eA.x, v.z, fmaf(-eA.y, v.w, accr[0][1]));
                accr[1][0] = fmaf(eA.z, v.x, fmaf(-eA.w, v.y, accr[1][0]));
                accr[1][1] = fmaf(eA.z, v.z, fmaf(-eA.w, v.w, accr[1][1]));
                accr[2][0] = fmaf(eB.x, v.x, fmaf(-eB.y, v.y, accr[2][0]));
                accr[2][1] = fmaf(eB.x, v.z, fmaf(-eB.y, v.w, accr[2][1]));
                accr[3][0] = fmaf(eB.z, v.x, fmaf(-eB.w, v.y, accr[3][0]));
                accr[3][1] = fmaf(eB.z, v.z, fmaf(-eB.w, v.w, accr[3][1]));
            }
        }
        __syncthreads();
    }
    // finalize: pr = x1 + x2/(H*W); write back; stats
    float* xp = &g_x1[(size_t)(b * C + k) * HW];
    float s = 0.f, ss = 0.f;
    if (tid < 240 && z0 < H) {
#pragma unroll
        for (int zi = 0; zi < 4; zi++) {
            int z = z0 + zi;
            if (z < H) {
#pragma unroll
                for (int xi = 0; xi < 2; xi++) {
                    int id = z * W + x0 + xi;
                    float v = xp[id] + accr[zi][xi] * (1.0f / (H * W));
                    xp[id] = v; s += v; ss += v * v;
                }
            }
        }
    }
    for (int off = 32; off; off >>= 1) { s += __shfl_down(s, off); ss += __shfl_down(ss, off); }
    if ((tid & 63) == 0) { red[tid >> 6] = s; red[4 + (tid >> 6)] = ss; }
    __syncthreads();
    if (tid == 0) {
        float S = red[0] + red[1] + red[2] + red[3];
        float SS = red[4] + red[5] + red[6] + red[7];
        float mean = S * (1.0f / HW);
        float var = SS * (1.0f / HW) - mean * mean;
        int bk = b * C + k;
        g_mu[bk] = mean; g_rstd[bk] = rsqrtf(var + EPS);
    }
}

// ---------------- h_next = sin( inorm(pr) + conv(h) + conv_b ) ----------------
constexpr int TILE = 128;
constexpr int NTILE = (HW + TILE - 1) / TILE;   // 13
__global__ __launch_bounds__(256) void k_comb(const float* __restrict__ cw,
                                              const float* __restrict__ cb, int l, int src) {
    int b = blockIdx.x / NTILE;
    int t0 = (blockIdx.x % NTILE) * TILE;
    int tid = threadIdx.x;
    __shared__ float shh[C * TILE];
    __shared__ float scw[C * C];
    __shared__ float smu[C], srs[C], scb[C];
    for (int i = tid; i < C * C; i += 256) scw[i] = cw[l * C * C + i];
    for (int i = tid; i < C; i += 256) {
        smu[i] = g_mu[b * C + i]; srs[i] = g_rstd[b * C + i]; scb[i] = cb[l * C + i];
    }
    for (int i = tid; i < C * TILE; i += 256) {
        int c = i / TILE, t = i % TILE; int hw = t0 + t;
        shh[i] = (hw < HW) ? g_h[src][(size_t)(b * C + c) * HW + hw] : 0.f;
    }
    __syncthreads();
    for (int i = tid; i < C * TILE; i += 256) {
        int o = i / TILE, t = i % TILE; int hw = t0 + t;
        if (hw >= HW) continue;
        float acc = scb[o];
        for (int ci = 0; ci < C; ci++) acc = fmaf(scw[o * C + ci], shh[ci * TILE + t], acc);
        float prn = (g_x1[(size_t)(b * C + o) * HW + hw] - smu[o]) * srs[o];
        g_h[src ^ 1][(size_t)(b * C + o) * HW + hw] = sinf(prn + acc);
    }
}

// ---------------- head: out = fc2( sin(fc1(h)) ) ----------------
__global__ __launch_bounds__(256) void k_head(const float* __restrict__ w1, const float* __restrict__ b1,
                                              const float* __restrict__ w2, const float* __restrict__ b2,
                                              float* __restrict__ out, int src) {
    __shared__ float sw1[128 * C];
    __shared__ float sb1[128], sw2[2 * 128];
    int tid = threadIdx.x;
    for (int i = tid; i < 128 * C; i += 256) sw1[i] = w1[i];
    for (int i = tid; i < 128; i += 256) sb1[i] = b1[i];
    for (int i = tid; i < 256; i += 256) sw2[i] = w2[i];
    __syncthreads();
    int pt = blockIdx.x * 256 + tid;               // b*HW + hw
    if (pt >= B * HW) return;
    int b = pt / HW, hw = pt % HW;
    float hv[C];
#pragma unroll
    for (int c = 0; c < C; c++) hv[c] = g_h[src][(size_t)(b * C + c) * HW + hw];
    float o0 = b2[0], o1 = b2[1];
    for (int j = 0; j < 128; j++) {
        float a = sb1[j];
#pragma unroll
        for (int c = 0; c < C; c++) a = fmaf(sw1[j * C + c], hv[c], a);
        float sv = sinf(a);
        o0 = fmaf(sw2[j], sv, o0);
        o1 = fmaf(sw2[128 + j], sv, o1);
    }
    out[pt * 2 + 0] = o0; out[pt * 2 + 1] = o1;
}

// ---------------- launcher ----------------
extern "C" void kernel_launch(void* const* d_in, const int* in_sizes, int n_in,
                              void* d_out, int out_size, void* d_ws, size_t ws_size,
                              hipStream_t stream) {
    const float* x    = (const float*)d_in[0];
    const float* fc0w = (const float*)d_in[1];
    const float* fc0b = (const float*)d_in[2];
    const float* p1   = (const float*)d_in[3];
    const float* p2   = (const float*)d_in[4];
    const float* res  = (const float*)d_in[5];
    const float* cw   = (const float*)d_in[6];
    const float* cb   = (const float*)d_in[7];
    const float* w1   = (const float*)d_in[8];
    const float* b1   = (const float*)d_in[9];
    const float* w2   = (const float*)d_in[10];
    const float* b2   = (const float*)d_in[11];
    float* out = (float*)d_out;

    k_tw<<<(H * H + W * W + 255) / 256, 256, 0, stream>>>();
    k_fc0<<<(B * C * HW + 255) / 256, 256, 0, stream>>>(x, fc0w, fc0b);
    int src = 0;
    for (int l = 0; l < NL; l++) {
        k_fft<<<B * C, 256, 0, stream>>>(src);
        k_tables<<<C * C, 256, 0, stream>>>(p1, p2, l);
        k_S<<<C * C, 256, 0, stream>>>(res, l);
        k_res1<<<B * C, 256, 0, stream>>>();
        k_ifft<<<B * C, 256, 0, stream>>>();
        k_r2a<<<C * C, 256, 0, stream>>>(res, l);
        k_r2b<<<(B * C * M1 * M2 + 255) / 256, 256, 0, stream>>>();
        k_x2<<<B * C, 256, 0, stream>>>();
        k_comb<<<B * NTILE, 256, 0, stream>>>(cw, cb, l, src);
        src ^= 1;
    }
    k_head<<<(B * HW + 255) / 256, 256, 0, stream>>>(w1, b1, w2, b2, out, src);
}

// Round 4
// 2117.625 us; speedup vs baseline: 1.5403x; 1.0416x over previous
//
#include <hip/hip_runtime.h>
#include <math.h>

#define DI __device__ __forceinline__

constexpr int B = 16, H = 41, W = 40, C = 48, M1 = 12, M2 = 12, NL = 4;
constexpr int HW = H * W;                  // 1640
constexpr float EPS = 1e-5f;
constexpr float PI_F = 3.14159265358979323846f;

// ---------------- static device scratch (compile-time shapes) ----------------
__device__ float  g_h[2][B * C * HW];      // ping-pong activations [b][c][hw]
__device__ float2 g_alpha[B * C * HW];     // fft2(inorm(h))
__device__ float2 g_inv1[C * C * M1 * H];  // [i*C+k][p][o]
__device__ float2 g_inv2[C * C * M2 * W];  // [i*C+k][q][x]
__device__ float2 g_E1[C * C * M1 * H];    // exp(p1 * TX)  [pk][p][z]
__device__ float2 g_E2[C * C * M2 * W];    // exp(p2 * TY)  [pk][q][x]
__device__ float2 g_S[C * C * HW];         // [i*C+k][o*W+x]
__device__ float2 g_res1[B * C * HW];
__device__ float  g_x1[B * C * HW];        // pr2d output accumulator (real)
__device__ float2 g_r2[B * C * M1 * M2];
__device__ float2 g_Zr[C * C][B * M1 * M2]; // per-(i,k) res-scaled Z, reduced over i by k_r2b
__device__ float  g_xpart[3][B * C][HW];   // k_x2p partial sums over ci-thirds
__device__ float  g_mu[B * C];
__device__ float  g_rstd[B * C];
__device__ float2 g_wfh[H * H];            // e^{-2pi i o h / H}
__device__ float2 g_wfw[W * W];            // e^{-2pi i x w / W}

// ---------------- complex helpers ----------------
DI float2 cmadd(float2 a, float2 b, float2 acc) {
    acc.x = fmaf(a.x, b.x, fmaf(-a.y, b.y, acc.x));
    acc.y = fmaf(a.x, b.y, fmaf(a.y, b.x, acc.y));
    return acc;
}
DI float2 cmul(float2 a, float2 b) {
    return make_float2(a.x * b.x - a.y * b.y, a.x * b.y + a.y * b.x);
}

// ---------------- twiddle tables ----------------
__global__ void k_tw() {
    int tid = blockIdx.x * 256 + threadIdx.x;
    if (tid < H * H) {
        int o = tid / H, h = tid % H;
        float ph = -2.0f * PI_F * (float)((o * h) % H) / (float)H;
        float s, c; sincosf(ph, &s, &c);
        g_wfh[tid] = make_float2(c, s);
    }
    int t2 = tid - H * H;
    if (t2 >= 0 && t2 < W * W) {
        int o = t2 / W, w = t2 % W;
        float ph = -2.0f * PI_F * (float)((o * w) % W) / (float)W;
        float s, c; sincosf(ph, &s, &c);
        g_wfw[t2] = make_float2(c, s);
    }
}

// ---------------- fc0 + grid concat ----------------
__global__ void k_fc0(const float* __restrict__ x, const float* __restrict__ w,
                      const float* __restrict__ bias) {
    int idx = blockIdx.x * 256 + threadIdx.x;
    if (idx >= B * C * HW) return;
    int hw = idx % HW; int bc = idx / HW; int c = bc % C; int b = bc / C;
    int hh = hw / W, ww = hw % W;
    float xv = x[b * HW + hw];
    float gx = hh * (1.0f / (H - 1));
    float gy = ww * (1.0f / (W - 1));
    g_h[0][idx] = fmaf(w[c * 3 + 0], xv, fmaf(w[c * 3 + 1], gx, fmaf(w[c * 3 + 2], gy, bias[c])));
}

// ---------------- instance-norm + fft2 (per b,c) ----------------
__global__ __launch_bounds__(256) void k_fft(int src) {
    int bid = blockIdx.x;                  // b*C + c
    const float* hp = &g_h[src][(size_t)bid * HW];
    __shared__ float sh[HW];
    __shared__ float2 st[HW];
    __shared__ float red[8];
    int tid = threadIdx.x;
    float s = 0.f, ss = 0.f;
    for (int i = tid; i < HW; i += 256) { float v = hp[i]; sh[i] = v; s += v; ss += v * v; }
    for (int off = 32; off; off >>= 1) { s += __shfl_down(s, off); ss += __shfl_down(ss, off); }
    if ((tid & 63) == 0) { red[tid >> 6] = s; red[4 + (tid >> 6)] = ss; }
    __syncthreads();
    if (tid == 0) {
        float S = red[0] + red[1] + red[2] + red[3];
        float SS = red[4] + red[5] + red[6] + red[7];
        float mean = S * (1.0f / HW);
        float var = SS * (1.0f / HW) - mean * mean;
        red[0] = mean; red[1] = rsqrtf(var + EPS);
    }
    __syncthreads();
    float mean = red[0], rstd = red[1];
    for (int i = tid; i < HW; i += 256) sh[i] = (sh[i] - mean) * rstd;
    __syncthreads();
    // row DFT over h: st[o*W+w] = sum_h wfh[o,h] * sh[h,w]
    for (int i = tid; i < HW; i += 256) {
        int o = i / W, w = i % W;
        float2 acc = make_float2(0.f, 0.f);
        for (int h = 0; h < H; h++) {
            float v = sh[h * W + w];
            float2 tw = g_wfh[o * H + h];
            acc.x = fmaf(tw.x, v, acc.x); acc.y = fmaf(tw.y, v, acc.y);
        }
        st[i] = acc;
    }
    __syncthreads();
    // col DFT over w: alpha[o*W+x] = sum_w st[o,w] * wfw[x,w]
    float2* ap = &g_alpha[(size_t)bid * HW];
    for (int i = tid; i < HW; i += 256) {
        int o = i / W, x = i % W;
        float2 acc = make_float2(0.f, 0.f);
        for (int w = 0; w < W; w++) acc = cmadd(st[o * W + w], g_wfw[x * W + w], acc);
        ap[i] = acc;
    }
}

// ---------------- pole tables: inv1, inv2, E1, E2 (per i,k pair) ----------------
__global__ void k_tables(const float* __restrict__ p1, const float* __restrict__ p2, int l) {
    int pk = blockIdx.x;                   // i*C + k
    int tid = threadIdx.x;
    const float* pp1 = p1 + (size_t)(l * C * C + pk) * M1 * 2;
    const float* pp2 = p2 + (size_t)(l * C * C + pk) * M2 * 2;
    float2* inv1 = &g_inv1[(size_t)pk * M1 * H];
    float2* e1   = &g_E1[(size_t)pk * M1 * H];
    for (int i = tid; i < M1 * H; i += 256) {
        int p = i / H, o = i % H;
        float pr = pp1[p * 2], pi = pp1[p * 2 + 1];
        int ko = (o <= H / 2) ? o : o - H;           // fftfreq, H=41 odd
        float lam = (40.0f / 41.0f) * (float)ko;     // Im(LAM1)
        float a = -pr, b = lam - pi;
        float d = 1.0f / (a * a + b * b);
        inv1[i] = make_float2(a * d, -b * d);
        float t = o * (2.0f * PI_F / (H - 1));       // TX[z]
        float er = expf(pr * t);
        float sn, cs; sincosf(pi * t, &sn, &cs);
        e1[i] = make_float2(er * cs, er * sn);
    }
    float2* inv2 = &g_inv2[(size_t)pk * M2 * W];
    float2* e2   = &g_E2[(size_t)pk * M2 * W];
    for (int i = tid; i < M2 * W; i += 256) {
        int q = i / W, x = i % W;
        float pr = pp2[q * 2], pi = pp2[q * 2 + 1];
        int kx = (x < W / 2) ? x : x - W;            // fftfreq, W=40 even
        float lam = (2.0f * PI_F * 39.0f / 600.0f) * (float)kx;  // Im(LAM2)
        float a = -pr, b = lam - pi;
        float d = 1.0f / (a * a + b * b);
        inv2[i] = make_float2(a * d, -b * d);
        float t = x * (15.0f / (W - 1));             // TY[x]
        float er = expf(pr * t);
        float sn, cs; sincosf(pi * t, &sn, &cs);
        e2[i] = make_float2(er * cs, er * sn);
    }
}

// ---------------- S[i,k,o,x] = sum_p inv1[p,o] * (sum_q res[p,q] inv2[q,x]) ----------------
__global__ __launch_bounds__(256) void k_S(const float* __restrict__ res_in, int l) {
    int pk = blockIdx.x;
    int tid = threadIdx.x;
    __shared__ float2 sres[M1 * M2], sinv1[M1 * H], sinv2[M2 * W], sT[M1 * W];
    const float2* rp = (const float2*)res_in + (size_t)(l * C * C + pk) * M1 * M2;
    for (int i = tid; i < M1 * M2; i += 256) sres[i] = rp[i];
    for (int i = tid; i < M1 * H; i += 256) sinv1[i] = g_inv1[(size_t)pk * M1 * H + i];
    for (int i = tid; i < M2 * W; i += 256) sinv2[i] = g_inv2[(size_t)pk * M2 * W + i];
    __syncthreads();
    for (int i = tid; i < M1 * W; i += 256) {
        int p = i / W, x = i % W;
        float2 acc = make_float2(0.f, 0.f);
        for (int q = 0; q < M2; q++) acc = cmadd(sres[p * M2 + q], sinv2[q * W + x], acc);
        sT[i] = acc;
    }
    __syncthreads();
    float2* sp = &g_S[(size_t)pk * HW];
    for (int i = tid; i < HW; i += 256) {
        int o = i / W, x = i % W;
        float2 acc = make_float2(0.f, 0.f);
        for (int p = 0; p < M1; p++) acc = cmadd(sinv1[p * H + o], sT[p * W + x], acc);
        sp[i] = acc;
    }
}

// ---------------- res1[b,k,hw-half] = sum_i alpha[b,i,·] * S[i,k,·] ----------------
__global__ __launch_bounds__(256) void k_res1() {
    // XCD-aware remap: same-k blocks cluster on one XCD (S k-slice L2-resident)
    int bid = blockIdx.x;
    int xcd = bid & 7, idx = bid >> 3;             // idx 0..191
    int half = idx & 1; idx >>= 1;                 // 0..95
    int k = (idx / B) * 8 + xcd;
    int b = idx % B;
    int base = half * (HW / 2);                    // 820 per half
    int tid = threadIdx.x;
    float2 acc[4];
#pragma unroll
    for (int j = 0; j < 4; j++) acc[j] = make_float2(0.f, 0.f);
    for (int i = 0; i < C; i++) {
        const float2* ap = &g_alpha[(size_t)(b * C + i) * HW + base];
        const float2* sp = &g_S[(size_t)(i * C + k) * HW + base];
#pragma unroll
        for (int j = 0; j < 4; j++) {
            int idx2 = tid + j * 256;
            if (idx2 < HW / 2) acc[j] = cmadd(ap[idx2], sp[idx2], acc[j]);
        }
    }
    float2* rp = &g_res1[(size_t)(b * C + k) * HW + base];
#pragma unroll
    for (int j = 0; j < 4; j++) { int idx2 = tid + j * 256; if (idx2 < HW / 2) rp[idx2] = acc[j]; }
}

// ---------------- x1 = ifft2(res1).real ----------------
__global__ __launch_bounds__(256) void k_ifft() {
    int bid = blockIdx.x; int tid = threadIdx.x;
    __shared__ float2 s0[HW], s1[HW];
    const float2* rp = &g_res1[(size_t)bid * HW];
    for (int i = tid; i < HW; i += 256) s0[i] = rp[i];
    __syncthreads();
    // inverse over o: s1[h,x] = sum_o s0[o,x] * conj(wfh[o,h])
    for (int i = tid; i < HW; i += 256) {
        int h = i / W, x = i % W;
        float2 acc = make_float2(0.f, 0.f);
        for (int o = 0; o < H; o++) {
            float2 v = s0[o * W + x]; float2 tw = g_wfh[o * H + h];
            acc.x = fmaf(v.x, tw.x, fmaf(v.y, tw.y, acc.x));
            acc.y = fmaf(v.y, tw.x, fmaf(-v.x, tw.y, acc.y));
        }
        s1[i] = acc;
    }
    __syncthreads();
    float* xp = &g_x1[(size_t)bid * HW];
    for (int i = tid; i < HW; i += 256) {
        int h = i / W, w = i % W;
        float acc = 0.f;
        for (int x = 0; x < W; x++) {
            float2 v = s1[h * W + x]; float2 tw = g_wfw[x * W + w];
            acc = fmaf(v.x, tw.x, fmaf(v.y, tw.y, acc));  // Re(v * conj(tw))
        }
        xp[i] = acc * (1.0f / (H * W));
    }
}

// ---------------- k_r2a v2: per (i,k): Zr[b,p,q] = res ⊙ (inv1 @ alpha[b,i] @ inv2^T) ------
__global__ __launch_bounds__(256) void k_r2a(const float* __restrict__ res_in, int l) {
    // XCD-aware remap: same-i blocks on one XCD (alpha[:,i] slices L2-resident)
    int bid = blockIdx.x;
    int xcd = bid & 7, idx = bid >> 3;             // idx 0..287
    int i = (idx / C) * 8 + xcd;                   // 6 i's per XCD
    int k = idx % C;
    int pk = i * C + k;
    int tid = threadIdx.x;
    __shared__ float2 sY[4 * M1 * 41];             // 15.7 KB
    __shared__ float2 si1t[H * 16];                // transposed inv1 [o][p]
    __shared__ float2 si2[M2 * 41];                // [q*41 + x]
    __shared__ float2 sres[M1 * M2];
    for (int t = tid; t < M1 * H; t += 256) {
        int p = t / H, o = t % H;
        si1t[o * 16 + p] = g_inv1[(size_t)pk * M1 * H + t];
    }
    for (int t = tid; t < M2 * W; t += 256) {
        int q = t / W, x = t % W;
        si2[q * 41 + x] = g_inv2[(size_t)pk * M2 * W + t];
    }
    const float2* rp = (const float2*)res_in + (size_t)(l * C * C + pk) * M1 * M2;
    for (int t = tid; t < M1 * M2; t += 256) sres[t] = rp[t];
    __syncthreads();
    for (int c = 0; c < 4; c++) {
        if (c > 0) __syncthreads();                // prev Z done before sY overwrite
        if (tid < 160) {
            int bloc = tid / 40, x = tid % 40;
            int b = c * 4 + bloc;
            const float2* ap = &g_alpha[(size_t)(b * C + i) * HW + x];
            float2 yacc[12];
#pragma unroll
            for (int p = 0; p < 12; p++) yacc[p] = make_float2(0.f, 0.f);
            for (int o = 0; o < H; o++) {
                float2 a = ap[o * W];
                const float2* e = &si1t[o * 16];
#pragma unroll
                for (int p = 0; p < 12; p++) yacc[p] = cmadd(e[p], a, yacc[p]);
            }
#pragma unroll
            for (int p = 0; p < 12; p++) sY[(bloc * M1 + p) * 41 + x] = yacc[p];
        }
        __syncthreads();
        if (tid < 192) {
            int bloc = tid / 48, rem = tid % 48;
            int p = rem >> 2, qq = rem & 3;
            int q0 = qq * 3;
            float2 zacc[3];
#pragma unroll
            for (int j = 0; j < 3; j++) zacc[j] = make_float2(0.f, 0.f);
            const float2* yrow = &sY[(bloc * M1 + p) * 41];
            for (int x = 0; x < W; x++) {
                float2 y = yrow[x];
#pragma unroll
                for (int j = 0; j < 3; j++) zacc[j] = cmadd(y, si2[(q0 + j) * 41 + x], zacc[j]);
            }
            int b = c * 4 + bloc;
            float2* out = &g_Zr[pk][b * (M1 * M2) + p * M2 + q0];
#pragma unroll
            for (int j = 0; j < 3; j++) out[j] = cmul(sres[p * M2 + q0 + j], zacc[j]);
        }
    }
}

// ---------------- k_r2b: r2[b,k,p,q] = sum_i Zr[i*C+k][b,p,q] ----------------
__global__ __launch_bounds__(256) void k_r2b() {
    int t = blockIdx.x * 256 + threadIdx.x;        // < B*C*144
    if (t >= B * C * M1 * M2) return;
    int pq = t % (M1 * M2);
    int k = (t / (M1 * M2)) % C;
    int b = t / (M1 * M2 * C);
    float2 acc = make_float2(0.f, 0.f);
    for (int i = 0; i < C; i++) {
        float2 v = g_Zr[i * C + k][b * (M1 * M2) + pq];
        acc.x += v.x; acc.y += v.y;
    }
    g_r2[(size_t)(b * C + k) * (M1 * M2) + pq] = acc;
}

// ---------------- k_x2p: partial x2 over 16-ci chunk (part 0..2) ----------------
// grid 2304 = 8(xcd) * 3(part) * 96(k-chunk*b); LDS ~26KB -> 6 blocks/CU.
constexpr int XNCI = 2;
__global__ __launch_bounds__(256) void k_x2p() {
    int bid = blockIdx.x;
    int xcd = bid & 7, rest = bid >> 3;            // 0..287
    int part = rest % 3;
    int idx = rest / 3;                            // 0..95
    int k = (idx / B) * 8 + xcd;
    int b = idx % B;
    int tid = threadIdx.x;
    __shared__ float2 sE1[XNCI * M1 * 44];         // [jp][z], z-padded to 44 (zeros)
    __shared__ float2 sV [XNCI * M1 * 40];         // [jp][x]
    __shared__ float2 sE2[XNCI * M2 * 41];         // [jq][x]
    __shared__ float2 sr2[XNCI * M1 * M2];
    int xh = tid % 20, zq = tid / 20;              // active: tid<240
    int x0 = xh * 2, z0 = zq * 4;
    float accr[4][2];
#pragma unroll
    for (int zi = 0; zi < 4; zi++) { accr[zi][0] = 0.f; accr[zi][1] = 0.f; }

    int cg0 = part * (C / XNCI / 3);               // 8 cg groups per part
    for (int cg = cg0; cg < cg0 + C / XNCI / 3; cg++) {
        for (int t = tid; t < XNCI * M1 * 44; t += 256) {
            int j = t / (M1 * 44), rem = t % (M1 * 44);
            int p = rem / 44, z = rem % 44;
            sE1[t] = (z < H) ? g_E1[(size_t)((cg * XNCI + j) * C + k) * (M1 * H) + p * H + z]
                             : make_float2(0.f, 0.f);
        }
        for (int t = tid; t < XNCI * M2 * W; t += 256) {
            int j = t / (M2 * W), rem = t % (M2 * W);
            sE2[(t / W) * 41 + (t % W)] = g_E2[(size_t)((cg * XNCI + j) * C + k) * (M2 * W) + rem];
        }
        for (int t = tid; t < XNCI * M1 * M2; t += 256) {
            int j = t / (M1 * M2);
            sr2[t] = g_r2[(size_t)(b * C + cg * XNCI + j) * (M1 * M2) + (t % (M1 * M2))];
        }
        __syncthreads();
        // V[jp][x] = sum_q r2[j][p,q] * E2[j][q,x]
        for (int r = 0; r < 4; r++) {
            int id = tid + r * 256;
            if (id < XNCI * M1 * W) {
                int j = id / (M1 * W), rem = id % (M1 * W);
                int p = rem / W, x = rem % W;
                float2 a = make_float2(0.f, 0.f);
#pragma unroll
                for (int q = 0; q < M2; q++)
                    a = cmadd(sr2[j * (M1 * M2) + p * M2 + q], sE2[(j * M2 + q) * 41 + x], a);
                sV[(j * M1 + p) * 40 + x] = a;
            }
        }
        __syncthreads();
        // accr[z,x] += Re( E1[jp][z] * V[jp][x] )
        if (tid < 240 && z0 < H) {
            for (int jp = 0; jp < XNCI * M1; jp++) {
                float4 v  = *(const float4*)&sV[jp * 40 + x0];
                float4 eA = *(const float4*)&sE1[jp * 44 + z0];
                float4 eB = *(const float4*)&sE1[jp * 44 + z0 + 2];
                accr[0][0] = fmaf(eA.x, v.x, fmaf(-eA.y, v.y, accr[0][0]));
                accr[0][1] = fmaf(eA.x, v.z, fmaf(-eA.y, v.w, accr[0][1]));
                accr[1][0] = fmaf(eA.z, v.x, fmaf(-eA.w, v.y, accr[1][0]));
                accr[1][1] = fmaf(eA.z, v.z, fmaf(-eA.w, v.w, accr[1][1]));
                accr[2][0] = fmaf(eB.x, v.x, fmaf(-eB.y, v.y, accr[2][0]));
                accr[2][1] = fmaf(eB.x, v.z, fmaf(-eB.y, v.w, accr[2][1]));
                accr[3][0] = fmaf(eB.z, v.x, fmaf(-eB.w, v.y, accr[3][0]));
                accr[3][1] = fmaf(eB.z, v.z, fmaf(-eB.w, v.w, accr[3][1]));
            }
        }
        __syncthreads();
    }
    float* op = &g_xpart[part][b * C + k][0];
    if (tid < 240 && z0 < H) {
#pragma unroll
        for (int zi = 0; zi < 4; zi++) {
            int z = z0 + zi;
            if (z < H) { op[z * W + x0] = accr[zi][0]; op[z * W + x0 + 1] = accr[zi][1]; }
        }
    }
}

// ---------------- k_fin: pr = x1 + (sum parts)/(H*W); stats ----------------
__global__ __launch_bounds__(256) void k_fin() {
    int bid = blockIdx.x;                          // b*C + k
    int tid = threadIdx.x;
    __shared__ float red[8];
    float* xp = &g_x1[(size_t)bid * HW];
    const float* p0 = &g_xpart[0][bid][0];
    const float* p1 = &g_xpart[1][bid][0];
    const float* p2 = &g_xpart[2][bid][0];
    float s = 0.f, ss = 0.f;
    for (int i = tid; i < HW; i += 256) {
        float v = xp[i] + (p0[i] + p1[i] + p2[i]) * (1.0f / (H * W));
        xp[i] = v; s += v; ss += v * v;
    }
    for (int off = 32; off; off >>= 1) { s += __shfl_down(s, off); ss += __shfl_down(ss, off); }
    if ((tid & 63) == 0) { red[tid >> 6] = s; red[4 + (tid >> 6)] = ss; }
    __syncthreads();
    if (tid == 0) {
        float S = red[0] + red[1] + red[2] + red[3];
        float SS = red[4] + red[5] + red[6] + red[7];
        float mean = S * (1.0f / HW);
        float var = SS * (1.0f / HW) - mean * mean;
        g_mu[bid] = mean; g_rstd[bid] = rsqrtf(var + EPS);
    }
}

// ---------------- h_next = sin( inorm(pr) + conv(h) + conv_b ) ----------------
constexpr int TILE = 128;
constexpr int NTILE = (HW + TILE - 1) / TILE;   // 13
__global__ __launch_bounds__(256) void k_comb(const float* __restrict__ cw,
                                              const float* __restrict__ cb, int l, int src) {
    int b = blockIdx.x / NTILE;
    int t0 = (blockIdx.x % NTILE) * TILE;
    int tid = threadIdx.x;
    __shared__ float shh[C * TILE];
    __shared__ float scw[C * C];
    __shared__ float smu[C], srs[C], scb[C];
    for (int i = tid; i < C * C; i += 256) scw[i] = cw[l * C * C + i];
    for (int i = tid; i < C; i += 256) {
        smu[i] = g_mu[b * C + i]; srs[i] = g_rstd[b * C + i]; scb[i] = cb[l * C + i];
    }
    for (int i = tid; i < C * TILE; i += 256) {
        int c = i / TILE, t = i % TILE; int hw = t0 + t;
        shh[i] = (hw < HW) ? g_h[src][(size_t)(b * C + c) * HW + hw] : 0.f;
    }
    __syncthreads();
    for (int i = tid; i < C * TILE; i += 256) {
        int o = i / TILE, t = i % TILE; int hw = t0 + t;
        if (hw >= HW) continue;
        float acc = scb[o];
        for (int ci = 0; ci < C; ci++) acc = fmaf(scw[o * C + ci], shh[ci * TILE + t], acc);
        float prn = (g_x1[(size_t)(b * C + o) * HW + hw] - smu[o]) * srs[o];
        g_h[src ^ 1][(size_t)(b * C + o) * HW + hw] = sinf(prn + acc);
    }
}

// ---------------- head: out = fc2( sin(fc1(h)) ) ----------------
__global__ __launch_bounds__(256) void k_head(const float* __restrict__ w1, const float* __restrict__ b1,
                                              const float* __restrict__ w2, const float* __restrict__ b2,
                                              float* __restrict__ out, int src) {
    __shared__ float sw1[128 * C];
    __shared__ float sb1[128], sw2[2 * 128];
    int tid = threadIdx.x;
    for (int i = tid; i < 128 * C; i += 256) sw1[i] = w1[i];
    for (int i = tid; i < 128; i += 256) sb1[i] = b1[i];
    for (int i = tid; i < 256; i += 256) sw2[i] = w2[i];
    __syncthreads();
    int pt = blockIdx.x * 256 + tid;               // b*HW + hw
    if (pt >= B * HW) return;
    int b = pt / HW, hw = pt % HW;
    float hv[C];
#pragma unroll
    for (int c = 0; c < C; c++) hv[c] = g_h[src][(size_t)(b * C + c) * HW + hw];
    float o0 = b2[0], o1 = b2[1];
    for (int j = 0; j < 128; j++) {
        float a = sb1[j];
#pragma unroll
        for (int c = 0; c < C; c++) a = fmaf(sw1[j * C + c], hv[c], a);
        float sv = sinf(a);
        o0 = fmaf(sw2[j], sv, o0);
        o1 = fmaf(sw2[128 + j], sv, o1);
    }
    out[pt * 2 + 0] = o0; out[pt * 2 + 1] = o1;
}

// ---------------- launcher ----------------
extern "C" void kernel_launch(void* const* d_in, const int* in_sizes, int n_in,
                              void* d_out, int out_size, void* d_ws, size_t ws_size,
                              hipStream_t stream) {
    const float* x    = (const float*)d_in[0];
    const float* fc0w = (const float*)d_in[1];
    const float* fc0b = (const float*)d_in[2];
    const float* p1   = (const float*)d_in[3];
    const float* p2   = (const float*)d_in[4];
    const float* res  = (const float*)d_in[5];
    const float* cw   = (const float*)d_in[6];
    const float* cb   = (const float*)d_in[7];
    const float* w1   = (const float*)d_in[8];
    const float* b1   = (const float*)d_in[9];
    const float* w2   = (const float*)d_in[10];
    const float* b2   = (const float*)d_in[11];
    float* out = (float*)d_out;

    k_tw<<<(H * H + W * W + 255) / 256, 256, 0, stream>>>();
    k_fc0<<<(B * C * HW + 255) / 256, 256, 0, stream>>>(x, fc0w, fc0b);
    int src = 0;
    for (int l = 0; l < NL; l++) {
        k_fft<<<B * C, 256, 0, stream>>>(src);
        k_tables<<<C * C, 256, 0, stream>>>(p1, p2, l);
        k_S<<<C * C, 256, 0, stream>>>(res, l);
        k_res1<<<B * C * 2, 256, 0, stream>>>();
        k_ifft<<<B * C, 256, 0, stream>>>();
        k_r2a<<<C * C, 256, 0, stream>>>(res, l);
        k_r2b<<<(B * C * M1 * M2 + 255) / 256, 256, 0, stream>>>();
        k_x2p<<<3 * B * C, 256, 0, stream>>>();
        k_fin<<<B * C, 256, 0, stream>>>();
        k_comb<<<B * NTILE, 256, 0, stream>>>(cw, cb, l, src);
        src ^= 1;
    }
    k_head<<<(B * HW + 255) / 256, 256, 0, stream>>>(w1, b1, w2, b2, out, src);
}